// Round 13
// baseline (124.691 us; speedup 1.0000x reference)
//
#include <hip/hip_runtime.h>
#include <hip/hip_bf16.h>

typedef short s16x8 __attribute__((ext_vector_type(8)));
typedef float f32x4 __attribute__((ext_vector_type(4)));
typedef unsigned long long u64;

static __device__ __forceinline__ unsigned short f2bf(float f){
    unsigned int u = __float_as_uint(f);
    u += 0x7fffu + ((u >> 16) & 1u);
    return (unsigned short)(u >> 16);
}
static __device__ __forceinline__ float bf2f(unsigned short h){
    return __uint_as_float(((unsigned int)h) << 16);
}

// ---------------- workspace layout (float offsets) ----------------
static const size_t OFF_QKV   = 0;         // bf16[256][512][64]
static const size_t OFF_A1    = 8388608;
static const size_t OFF_B1    = 8389120;
static const size_t OFF_P2    = 8389632;
static const size_t OFF_A2    = 8414208;
static const size_t OFF_ATTN  = 8414272;   // bf16[256][16][16][64]
static const size_t OFF_ATTNE = 12608576;  // bf16[256][16][16][64]
static const size_t OFF_A3    = 16802880;
static const size_t OFF_B3    = 16803392;
static const size_t OFF_P1G   = 16803904;  // float[128 by][512 o][2]  (512 KB)
static const size_t OFF_P3G   = 16934976;  // float[4096 bx][64]       (1 MB)
static const size_t OFF_IMGQ  = 17197120;  // u16[128][24]
static const size_t OFF_IMGV  = 17198656;  // u16[16][136]
static const size_t OFF_ZQK   = 17199744;  // u64[4096][256][4]
static const size_t OFF_ZQE   = 25588352;
static const size_t OFF_ZKE   = 33976960;
// transients (dead before pass2<1> writes attn/attne):
static const size_t OFF_XTH = OFF_ATTN;               // bf16[16384][256]
static const size_t OFF_WH  = OFF_ATTN + 4194304;     // bf16[512][256]
static const size_t OFF_WL  = OFF_ATTN + 4259840;     // bf16[512][256]

// ---------------- Kernel 0: prep (x transpose | w split | rel_emb images) ----------------
__global__ __launch_bounds__(256) void k_prep(const float* __restrict__ x,
                                              const float* __restrict__ w,
                                              const float* __restrict__ remb,
                                              unsigned short* __restrict__ xTh,
                                              unsigned short* __restrict__ wh,
                                              unsigned short* __restrict__ wl,
                                              unsigned short* __restrict__ imgQK,
                                              unsigned short* __restrict__ imgV)
{
    const int bid = blockIdx.x;
    const int tid = threadIdx.x;
    if (bid < 256) {           // ---- split+transpose x
        __shared__ unsigned short xs[64*264];
        const int n = bid;
        const int b = n >> 6, h = n & 63;
        const float* xbase = x + (size_t)b*256*4096 + (size_t)h*64;
        const int iw = tid >> 2, cch = (tid & 3) * 64;
        const size_t row = (size_t)n*64 + iw;
        {
            const int c = tid;
            #pragma unroll 4
            for (int ic = 0; ic < 16; ++ic) {
                const float4 v = *(const float4*)&xbase[(size_t)c*4096 + ic*4];
                const float vv[4] = {v.x, v.y, v.z, v.w};
                #pragma unroll
                for (int u = 0; u < 4; ++u) xs[(ic*4+u)*264 + c] = f2bf(vv[u]);
            }
        }
        __syncthreads();
        #pragma unroll
        for (int u8 = 0; u8 < 8; ++u8)
            *(s16x8*)&xTh[row*256 + cch + u8*8] = *(const s16x8*)&xs[iw*264 + cch + u8*8];
        return;
    }
    if (bid < 384) {           // ---- split w
        const int t4 = (bid - 256)*256 + tid;
        const float4 v = *(const float4*)&w[(size_t)t4*4];
        const float vv[4] = {v.x, v.y, v.z, v.w};
        ushort4 hi4, lo4;
        unsigned short* hp = (unsigned short*)&hi4;
        unsigned short* lp = (unsigned short*)&lo4;
        #pragma unroll
        for (int u = 0; u < 4; ++u) {
            hp[u] = f2bf(vv[u]);
            lp[u] = f2bf(vv[u] - bf2f(hp[u]));
        }
        *(ushort4*)&wh[(size_t)t4*4] = hi4;
        *(ushort4*)&wl[(size_t)t4*4] = lo4;
        return;
    }
    // bid == 384: rel_emb images
    if (tid < 128) {
        const int d = tid;
        u64 q0 = 0, q1 = 0, k0 = 0, k1 = 0;
        if (d < 127) {
            #pragma unroll
            for (int c = 0; c < 4; ++c) q0 |= (u64)f2bf(remb[c*127 + d])      << (16*c);
            #pragma unroll
            for (int c = 0; c < 4; ++c) q1 |= (u64)f2bf(remb[(4+c)*127 + d])  << (16*c);
            #pragma unroll
            for (int c = 0; c < 4; ++c) k0 |= (u64)f2bf(remb[(8+c)*127 + d])  << (16*c);
            #pragma unroll
            for (int c = 0; c < 4; ++c) k1 |= (u64)f2bf(remb[(12+c)*127 + d]) << (16*c);
        }
        u64* row = (u64*)(imgQK + (size_t)d*24);
        row[0] = q0; row[1] = q1; row[2] = k0; row[3] = k1; row[4] = 0; row[5] = 0;
    } else {
        for (int e = tid - 128; e < 2176; e += 128) {
            const int cv = e / 136, dd = e - cv*136;
            imgV[e] = (dd < 127) ? f2bf(remb[(16+cv)*127 + dd]) : (unsigned short)0;
        }
    }
}

// ---------------- Kernel 1: qkv(bf16) = (wh+wl).xh via MFMA + bn1 partials (no atomics) ----------------
__global__ __launch_bounds__(512) void k_qkv_mfma(const unsigned short* __restrict__ wh,
                                                  const unsigned short* __restrict__ wl,
                                                  const unsigned short* __restrict__ xTh,
                                                  unsigned short* __restrict__ qkvb,
                                                  float* __restrict__ p1g)
{
    __shared__ char smraw[34816];
    unsigned short* const Ah = (unsigned short*)smraw;           // [128][40]
    unsigned short* const Al = Ah + 5120;
    unsigned short* const Bh = Al + 5120;
    unsigned short* const Cl = (unsigned short*)smraw;           // [128][136] overlay
    float* const part = (float*)(smraw + 20480);                 // [4][128][2] overlay on Bh
    const int o0   = blockIdx.x * 128;
    const int col0 = blockIdx.y * 128;
    const int tid = threadIdx.x;
    const int w = tid >> 6, l = tid & 63, lb = l & 15, h = l >> 4;
    const int oq = (w >> 2) * 64, cq = (w & 3) * 32;

    f32x4 acc[4][2];
    #pragma unroll
    for (int m = 0; m < 4; ++m)
        #pragma unroll
        for (int nn = 0; nn < 2; ++nn) { acc[m][nn][0]=0.f; acc[m][nn][1]=0.f; acc[m][nn][2]=0.f; acc[m][nn][3]=0.f; }

    const int srow = tid >> 2, sc8 = (tid & 3) * 8;
    int4 rA, rL, rB;
    rA = *(const int4*)(wh  + (size_t)(o0  +srow)*256 + sc8);
    rL = *(const int4*)(wl  + (size_t)(o0  +srow)*256 + sc8);
    rB = *(const int4*)(xTh + (size_t)(col0+srow)*256 + sc8);
    *(int4*)&Ah[srow*40 + sc8] = rA;
    *(int4*)&Al[srow*40 + sc8] = rL;
    *(int4*)&Bh[srow*40 + sc8] = rB;

    for (int step = 0; step < 8; ++step) {
        __syncthreads();
        if (step < 7) {
            const int kk = (step+1)*32;
            rA = *(const int4*)(wh  + (size_t)(o0  +srow)*256 + kk + sc8);
            rL = *(const int4*)(wl  + (size_t)(o0  +srow)*256 + kk + sc8);
            rB = *(const int4*)(xTh + (size_t)(col0+srow)*256 + kk + sc8);
        }
        s16x8 ah[4], al[4], bf[2];
        #pragma unroll
        for (int m = 0; m < 4; ++m)  ah[m] = *(const s16x8*)&Ah[(oq + m*16 + lb)*40 + h*8];
        #pragma unroll
        for (int m = 0; m < 4; ++m)  al[m] = *(const s16x8*)&Al[(oq + m*16 + lb)*40 + h*8];
        #pragma unroll
        for (int nn = 0; nn < 2; ++nn) bf[nn] = *(const s16x8*)&Bh[(cq + nn*16 + lb)*40 + h*8];
        #pragma unroll
        for (int m = 0; m < 4; ++m)
            #pragma unroll
            for (int nn = 0; nn < 2; ++nn) {
                acc[m][nn] = __builtin_amdgcn_mfma_f32_16x16x32_bf16(ah[m], bf[nn], acc[m][nn], 0,0,0);
                acc[m][nn] = __builtin_amdgcn_mfma_f32_16x16x32_bf16(al[m], bf[nn], acc[m][nn], 0,0,0);
            }
        __syncthreads();
        if (step < 7) {
            *(int4*)&Ah[srow*40 + sc8] = rA;
            *(int4*)&Al[srow*40 + sc8] = rL;
            *(int4*)&Bh[srow*40 + sc8] = rB;
        }
    }

    // ---- bn1 partials: shfl-reduce over lb, single-writer LDS slots, no atomics
    #pragma unroll
    for (int m = 0; m < 4; ++m)
        #pragma unroll
        for (int r = 0; r < 4; ++r) {
            float s  = acc[m][0][r] + acc[m][1][r];
            float s2 = acc[m][0][r]*acc[m][0][r] + acc[m][1][r]*acc[m][1][r];
            #pragma unroll
            for (int mk = 1; mk < 16; mk <<= 1) { s += __shfl_xor(s, mk); s2 += __shfl_xor(s2, mk); }
            if (lb == 0) {
                const int ol = oq + m*16 + h*4 + r;
                part[((w & 3)*128 + ol)*2 + 0] = s;
                part[((w & 3)*128 + ol)*2 + 1] = s2;
            }
        }
    __syncthreads();
    if (tid < 256) {
        const float v = part[tid] + part[256 + tid] + part[512 + tid] + part[768 + tid];
        p1g[((size_t)blockIdx.y*512 + o0)*2 + tid] = v;
    }
    __syncthreads();   // part reads done before Cl overlay

    #pragma unroll
    for (int m = 0; m < 4; ++m)
        #pragma unroll
        for (int nn = 0; nn < 2; ++nn)
            #pragma unroll
            for (int r = 0; r < 4; ++r)
                Cl[(oq + m*16 + h*4 + r)*136 + cq + nn*16 + lb] = f2bf(acc[m][nn][r]);
    __syncthreads();
    const int erow = tid >> 2, eseg = (tid & 3) * 16;
    #pragma unroll
    for (int h2 = 0; h2 < 2; ++h2) {
        unsigned short* dst = qkvb + ((size_t)((col0 >> 6) + h2)*512 + (o0 + erow))*64 + eseg;
        *(s16x8*)&dst[0] = *(const s16x8*)&Cl[erow*136 + h2*64 + eseg];
        *(s16x8*)&dst[8] = *(const s16x8*)&Cl[erow*136 + h2*64 + eseg + 8];
    }
}

// ---------------- Kernel 2: bn1 finalize ----------------
__global__ __launch_bounds__(256) void k_bn1fin(const float* __restrict__ p1g,
                                                const float* __restrict__ gamma,
                                                const float* __restrict__ beta,
                                                float* __restrict__ a1, float* __restrict__ b1)
{
    const int o = blockIdx.x*256 + threadIdx.x;
    float S = 0.f, S2 = 0.f;
    for (int by = 0; by < 128; ++by) {
        S  += p1g[((size_t)by*512 + o)*2];
        S2 += p1g[((size_t)by*512 + o)*2 + 1];
    }
    const float mean = S * (1.f/16384.f);
    const float var  = S2 * (1.f/16384.f) - mean*mean;
    const float A = gamma[o] * rsqrtf(var + 1e-5f);
    a1[o] = A;
    b1[o] = beta[o] - mean*A;
}

// ---------------- Kernels 3/5: per-(n,g) core ----------------
template<int PASSB>
__global__ __launch_bounds__(256) void k_pass2(const unsigned short* __restrict__ qkvb,
    const float* __restrict__ a1, const float* __restrict__ b1,
    const unsigned short* __restrict__ imgQK, const unsigned short* __restrict__ imgV,
    float* __restrict__ p2, const float* __restrict__ a2,
    u64* __restrict__ zqk, u64* __restrict__ zqe, u64* __restrict__ zke,
    unsigned short* __restrict__ attnb, unsigned short* __restrict__ attneb,
    float* __restrict__ p3g)
{
    extern __shared__ char sm[];
    const int bx = blockIdx.x, n = bx >> 4, g = bx & 15;
    const int tid = threadIdx.x;
    const int w = tid >> 6, l = tid & 63, lb = l & 15, h = l >> 4;
    const int i0 = w*16;
    const size_t bbase = ((size_t)bx*256 + tid)*4;
    const s16x8 z8 = {0,0,0,0,0,0,0,0};

    if (!PASSB) {
        unsigned short* const qkT    = (unsigned short*)sm;            // [64][16]
        unsigned short* const rembQK = (unsigned short*)(sm + 2048);   // [128][24]
        unsigned short (* const qeT)[72] = (unsigned short(*)[72])(sm + 8192);
        unsigned short (* const keT)[72] = (unsigned short(*)[72])(sm + 17408);
        float* const red = (float*)(sm + 26624);

        {
            const int4* gsrc = (const int4*)imgQK;
            int4* ldst = (int4*)rembQK;
            for (int t = tid; t < 384; t += 256) ldst[t] = gsrc[t];
        }
        {
            const int a = tid & 63, c0 = (tid >> 6) * 4;
            u64 pk = 0;
            #pragma unroll
            for (int u = 0; u < 4; ++u) {
                const int o = g*32 + c0 + u;
                const float val = a1[o] * bf2f(qkvb[((size_t)n*512 + o)*64 + a]) + b1[o];
                pk |= (u64)f2bf(val) << (16*u);
            }
            *(u64*)&qkT[a*16 + c0] = pk;
        }
        __syncthreads();

        float sqe=0.f, s2qe=0.f, ske=0.f, s2ke=0.f;
        {
            const int a0 = w*16;
            const s16x8 afr = (h < 2) ? *(const s16x8*)&qkT[(a0 + lb)*16 + h*8] : z8;
            #pragma unroll
            for (int dt = 0; dt < 8; ++dt) {
                const int dd = dt*16 + lb;
                const s16x8 bq = (h == 0) ? *(const s16x8*)&rembQK[dd*24 + 0] : z8;
                const s16x8 bk = (h == 1) ? *(const s16x8*)&rembQK[dd*24 + 8] : z8;
                f32x4 zz = {0.f,0.f,0.f,0.f};
                f32x4 cqf = __builtin_amdgcn_mfma_f32_16x16x32_bf16(afr, bq, zz, 0,0,0);
                f32x4 ckf = __builtin_amdgcn_mfma_f32_16x16x32_bf16(afr, bk, zz, 0,0,0);
                #pragma unroll
                for (int r = 0; r < 4; ++r) {
                    const int a = a0 + h*4 + r;
                    const int i = a + 63 - dd;
                    if (i >= 0 && i < 64) {
                        const float vq = cqf[r], vk = ckf[r];
                        qeT[i][a] = f2bf(vq);
                        keT[i][a] = f2bf(vk);
                        sqe += vq; s2qe += vq*vq; ske += vk; s2ke += vk*vk;
                    }
                }
            }
        }
        __syncthreads();

        f32x4 acc[4];
        #pragma unroll
        for (int jt = 0; jt < 4; ++jt) { acc[jt][0]=0.f; acc[jt][1]=0.f; acc[jt][2]=0.f; acc[jt][3]=0.f; }
        #pragma unroll
        for (int kc = 0; kc < 2; ++kc) {
            const s16x8 aq = *(const s16x8*)&qeT[i0 + lb][kc*32 + h*8];
            #pragma unroll
            for (int jt = 0; jt < 4; ++jt) {
                const s16x8 bk2 = *(const s16x8*)&keT[jt*16 + lb][kc*32 + h*8];
                acc[jt] = __builtin_amdgcn_mfma_f32_16x16x32_bf16(aq, bk2, acc[jt], 0,0,0);
            }
        }

        float sqk=0.f, s2qk=0.f;
        #pragma unroll
        for (int jt = 0; jt < 4; ++jt) {
            const u64 q4 = *(const u64*)&qeT[jt*16 + lb][i0 + 4*h];
            const u64 k4 = *(const u64*)&keT[jt*16 + lb][i0 + 4*h];
            zqe[bbase + jt] = q4;
            zke[bbase + jt] = k4;
            u64 pk = 0;
            #pragma unroll
            for (int r = 0; r < 4; ++r) {
                const float q_ = acc[jt][r];
                sqk += q_; s2qk += q_*q_;
                pk |= (u64)f2bf(q_) << (16*r);
            }
            zqk[bbase + jt] = pk;
        }

        float vals[6] = {sqk, s2qk, sqe, s2qe, ske, s2ke};
        #pragma unroll
        for (int q = 0; q < 6; ++q) {
            float v = vals[q];
            #pragma unroll
            for (int off = 32; off; off >>= 1) v += __shfl_xor(v, off);
            if (l == 0) red[w*6 + q] = v;
        }
        __syncthreads();
        if (tid < 6) p2[(size_t)bx*6 + tid] = red[tid] + red[6+tid] + red[12+tid] + red[18+tid];
        return;
    }

    // ================= PASS B =================
    unsigned short (* const PSt)[136]   = (unsigned short(*)[136])(sm);
    unsigned short (* const pT)[72]     = (unsigned short(*)[72])(sm + 17408);
    unsigned short (* const rembV)[136] = (unsigned short(*)[136])(sm + 26624);
    unsigned short (* const vbL)[72]    = (unsigned short(*)[72])(sm + 30976);
    float* const part3 = (float*)sm;    // [4][16][4] overlay (used after final barrier)

    {
        int4 z4i; z4i.x=z4i.y=z4i.z=z4i.w=0;
        int4* dst = (int4*)sm;
        for (int t = tid; t < 1088; t += 256) dst[t] = z4i;
    }
    {
        const int4* gsrc = (const int4*)imgV;
        int4* ldst = (int4*)rembV;
        for (int t = tid; t < 272; t += 256) ldst[t] = gsrc[t];
    }
    {
        const int cv = tid >> 4, ap = (tid & 15) * 4;
        const int o = g*32 + 16 + cv;
        const float A = a1[o], Bc = b1[o];
        const ushort4 vv = *(const ushort4*)&qkvb[((size_t)n*512 + o)*64 + ap];
        u64 pk = 0;
        pk |= (u64)f2bf(A*bf2f(vv.x) + Bc);
        pk |= (u64)f2bf(A*bf2f(vv.y) + Bc) << 16;
        pk |= (u64)f2bf(A*bf2f(vv.z) + Bc) << 32;
        pk |= (u64)f2bf(A*bf2f(vv.w) + Bc) << 48;
        *(u64*)&vbL[cv][ap] = pk;
    }

    const float c_qk = a2[g], c_qe = a2[16+g], c_ke = a2[32+g];
    float p[4][4];
    #pragma unroll
    for (int jt = 0; jt < 4; ++jt) {
        const u64 zq = zqk[bbase + jt];
        const u64 q4 = zqe[bbase + jt];
        const u64 k4 = zke[bbase + jt];
        #pragma unroll
        for (int r = 0; r < 4; ++r) {
            p[jt][r] = c_qk*bf2f((unsigned short)(zq >> (16*r)))
                     + c_qe*bf2f((unsigned short)(q4 >> (16*r)))
                     + c_ke*bf2f((unsigned short)(k4 >> (16*r)));
        }
    }
    #pragma unroll
    for (int r = 0; r < 4; ++r) {
        float m = fmaxf(fmaxf(p[0][r], p[1][r]), fmaxf(p[2][r], p[3][r]));
        #pragma unroll
        for (int mk = 8; mk; mk >>= 1) m = fmaxf(m, __shfl_xor(m, mk));
        float s = 0.f;
        #pragma unroll
        for (int jt = 0; jt < 4; ++jt) { p[jt][r] = __expf(p[jt][r] - m); s += p[jt][r]; }
        #pragma unroll
        for (int mk = 8; mk; mk >>= 1) s += __shfl_xor(s, mk);
        const float inv = 1.f / s;
        #pragma unroll
        for (int jt = 0; jt < 4; ++jt) p[jt][r] *= inv;
    }
    __syncthreads();

    #pragma unroll
    for (int jt = 0; jt < 4; ++jt)
        #pragma unroll
        for (int r = 0; r < 4; ++r) {
            const int i = i0 + 4*h + r, j = jt*16 + lb;
            const unsigned short pb = f2bf(p[jt][r]);
            pT[i][j] = pb;
            PSt[i][i + 63 - j] = pb;
        }
    __syncthreads();

    f32x4 accA = {0.f,0.f,0.f,0.f}, accE = {0.f,0.f,0.f,0.f};
    #pragma unroll
    for (int kc = 0; kc < 2; ++kc) {
        const s16x8 av = *(const s16x8*)&vbL[lb][kc*32 + h*8];
        const s16x8 bp = *(const s16x8*)&pT[i0 + lb][kc*32 + h*8];
        accA = __builtin_amdgcn_mfma_f32_16x16x32_bf16(av, bp, accA, 0,0,0);
    }
    #pragma unroll
    for (int kc = 0; kc < 4; ++kc) {
        const s16x8 ae = *(const s16x8*)&rembV[lb][kc*32 + h*8];
        const s16x8 bs = *(const s16x8*)&PSt[i0 + lb][kc*32 + h*8];
        accE = __builtin_amdgcn_mfma_f32_16x16x32_bf16(ae, bs, accE, 0,0,0);
    }
    unsigned short* aw = attnb  + ((size_t)n*16 + g)*1024;
    unsigned short* ew = attneb + ((size_t)n*16 + g)*1024;
    #pragma unroll
    for (int r = 0; r < 4; ++r) {
        aw[(4*h + r)*64 + i0 + lb] = f2bf(accA[r]);
        ew[(4*h + r)*64 + i0 + lb] = f2bf(accE[r]);
    }

    // ---- bn3 partials: shfl-reduce over lb (i), single-writer LDS, no atomics
    __syncthreads();   // all LDS reads (MFMA operands) complete before overlay
    #pragma unroll
    for (int r = 0; r < 4; ++r) {
        float sA = accA[r], sA2 = accA[r]*accA[r];
        float sE = accE[r], sE2 = accE[r]*accE[r];
        #pragma unroll
        for (int mk = 1; mk < 16; mk <<= 1) {
            sA += __shfl_xor(sA, mk); sA2 += __shfl_xor(sA2, mk);
            sE += __shfl_xor(sE, mk); sE2 += __shfl_xor(sE2, mk);
        }
        if (lb == 0) {
            const int c = 4*h + r;
            float* dst = part3 + ((w*16 + c) * 4);
            dst[0] = sA; dst[1] = sA2; dst[2] = sE; dst[3] = sE2;
        }
    }
    __syncthreads();
    if (tid < 64) {
        const float v = part3[tid] + part3[64 + tid] + part3[128 + tid] + part3[192 + tid];
        p3g[(size_t)bx*64 + tid] = v;
    }
}

// ---------------- Kernel 4: bn2 finalize ----------------
__global__ __launch_bounds__(256) void k_bn2(const float* __restrict__ p2,
                                             const float* __restrict__ gamma2,
                                             float* __restrict__ a2)
{
    const int ch = blockIdx.x*4 + (threadIdx.x >> 6);
    const int l = threadIdx.x & 63;
    const int kind = ch >> 4, g = ch & 15;
    float s = 0.f, s2 = 0.f;
    #pragma unroll
    for (int q = 0; q < 4; ++q) {
        const int nn = q*64 + l;
        const float* p = p2 + ((size_t)nn*16 + g)*6 + 2*kind;
        s += p[0]; s2 += p[1];
    }
    #pragma unroll
    for (int off = 32; off; off >>= 1) { s += __shfl_down(s, off); s2 += __shfl_down(s2, off); }
    if (l == 0) {
        const float mean = s * (1.f/1048576.f);
        const float var  = s2 * (1.f/1048576.f) - mean*mean;
        a2[ch] = gamma2[ch] * rsqrtf(var + 1e-5f);
    }
}

// ---------------- Kernel 6: bn3 finalize ----------------
__global__ __launch_bounds__(256) void k_bn3fin(const float* __restrict__ p3g,
                                                const float* __restrict__ gamma,
                                                const float* __restrict__ beta,
                                                float* __restrict__ a3, float* __restrict__ b3)
{
    const int o = blockIdx.x*256 + threadIdx.x;
    const int g = o >> 5, rem = o & 31, c = rem >> 1, sflag = rem & 1;
    const int base = c*4 + sflag*2;
    float S = 0.f, S2 = 0.f;
    for (int nn = 0; nn < 256; ++nn) {
        const float* p = p3g + ((size_t)nn*16 + g)*64 + base;
        S += p[0]; S2 += p[1];
    }
    const float mean = S * (1.f/16384.f);
    const float var  = S2 * (1.f/16384.f) - mean*mean;
    const float A = gamma[o] * rsqrtf(var + 1e-5f);
    a3[o] = A;
    b3[o] = beta[o] - mean*A;
}

// ---------------- Kernel 7: apply bn3, sum channel pairs, transpose (float4) ----------------
__global__ __launch_bounds__(256) void k_out(const unsigned short* __restrict__ attnb,
                                             const unsigned short* __restrict__ attneb,
                                             const float* __restrict__ a3,
                                             const float* __restrict__ b3,
                                             float* __restrict__ out)
{
    const int idx4 = blockIdx.x*256 + threadIdx.x;
    const int i4 = (idx4 & 15) * 4;
    const int h  = (idx4 >> 4) & 63;
    const int oc = (idx4 >> 10) & 255;
    const int b  = idx4 >> 18;
    const int g = oc >> 4, c = oc & 15;
    const int n = b*64 + h;
    const size_t src = ((size_t)n*16 + g)*1024 + (size_t)c*64 + i4;
    const int o0 = g*32 + 2*c;
    const float A0 = a3[o0], A1 = a3[o0+1], Bc = b3[o0] + b3[o0+1];
    const ushort4 va = *(const ushort4*)&attnb[src];
    const ushort4 ve = *(const ushort4*)&attneb[src];
    float4 o4;
    o4.x = A0*bf2f(va.x) + A1*bf2f(ve.x) + Bc;
    o4.y = A0*bf2f(va.y) + A1*bf2f(ve.y) + Bc;
    o4.z = A0*bf2f(va.z) + A1*bf2f(ve.z) + Bc;
    o4.w = A0*bf2f(va.w) + A1*bf2f(ve.w) + Bc;
    *(float4*)&out[((size_t)b*256 + oc)*4096 + h*64 + i4] = o4;
}

extern "C" void kernel_launch(void* const* d_in, const int* in_sizes, int n_in,
                              void* d_out, int out_size, void* d_ws, size_t ws_size,
                              hipStream_t stream) {
    const float* x    = (const float*)d_in[0];
    const float* w    = (const float*)d_in[1];
    const float* g1   = (const float*)d_in[2];
    const float* be1  = (const float*)d_in[3];
    const float* remb = (const float*)d_in[4];
    const float* g2   = (const float*)d_in[5];
    const float* g3   = (const float*)d_in[7];
    const float* be3  = (const float*)d_in[8];
    float* out = (float*)d_out;
    float* ws  = (float*)d_ws;

    unsigned short* qkvb  = (unsigned short*)(ws + OFF_QKV);
    float* a1    = ws + OFF_A1;
    float* b1    = ws + OFF_B1;
    float* p2    = ws + OFF_P2;
    float* a2    = ws + OFF_A2;
    unsigned short* attnb  = (unsigned short*)(ws + OFF_ATTN);
    unsigned short* attneb = (unsigned short*)(ws + OFF_ATTNE);
    float* a3    = ws + OFF_A3;
    float* b3    = ws + OFF_B3;
    float* p1g   = ws + OFF_P1G;
    float* p3g   = ws + OFF_P3G;
    unsigned short* imgQK = (unsigned short*)(ws + OFF_IMGQ);
    unsigned short* imgV  = (unsigned short*)(ws + OFF_IMGV);
    u64* zqk = (u64*)(ws + OFF_ZQK);
    u64* zqe = (u64*)(ws + OFF_ZQE);
    u64* zke = (u64*)(ws + OFF_ZKE);
    unsigned short* xTh = (unsigned short*)(ws + OFF_XTH);
    unsigned short* wh  = (unsigned short*)(ws + OFF_WH);
    unsigned short* wl  = (unsigned short*)(ws + OFF_WL);

    const int SHM_A = 26720;
    const int SHM_B = 33280;
    k_prep<<<385, 256, 0, stream>>>(x, w, remb, xTh, wh, wl, imgQK, imgV);
    k_qkv_mfma<<<dim3(4, 128), 512, 0, stream>>>(wh, wl, xTh, qkvb, p1g);
    k_bn1fin<<<2, 256, 0, stream>>>(p1g, g1, be1, a1, b1);
    k_pass2<0><<<4096, 256, SHM_A, stream>>>(qkvb, a1, b1, imgQK, imgV, p2, nullptr, zqk, zqe, zke, nullptr, nullptr, nullptr);
    k_bn2<<<12, 256, 0, stream>>>(p2, g2, a2);
    k_pass2<1><<<4096, 256, SHM_B, stream>>>(qkvb, a1, b1, imgQK, imgV, nullptr, a2, zqk, zqe, zke, attnb, attneb, p3g);
    k_bn3fin<<<2, 256, 0, stream>>>(p3g, g3, be3, a3, b3);
    k_out<<<4096, 256, 0, stream>>>(attnb, attneb, a3, b3, out);
}

// Round 14
// 113.997 us; speedup vs baseline: 1.0938x; 1.0938x over previous
//
#include <hip/hip_runtime.h>
#include <hip/hip_bf16.h>

typedef short s16x8 __attribute__((ext_vector_type(8)));
typedef float f32x4 __attribute__((ext_vector_type(4)));
typedef unsigned long long u64;

static __device__ __forceinline__ unsigned short f2bf(float f){
    unsigned int u = __float_as_uint(f);
    u += 0x7fffu + ((u >> 16) & 1u);
    return (unsigned short)(u >> 16);
}
static __device__ __forceinline__ float bf2f(unsigned short h){
    return __uint_as_float(((unsigned int)h) << 16);
}

// ---------------- workspace layout (float offsets) ----------------
static const size_t OFF_QKV   = 0;         // bf16[256][512][64]
static const size_t OFF_A1    = 8388608;
static const size_t OFF_B1    = 8389120;
static const size_t OFF_P2    = 8389632;
static const size_t OFF_A2    = 8414208;
static const size_t OFF_ATTN  = 8414272;   // bf16[256][16][16][64]
static const size_t OFF_ATTNE = 12608576;  // bf16[256][16][16][64]
static const size_t OFF_A3    = 16802880;
static const size_t OFF_B3    = 16803392;
static const size_t OFF_P1G   = 16803904;  // float[128 by][512 o][2]
static const size_t OFF_P3G   = 16934976;  // float[4096 bx][64]
static const size_t OFF_IMGQ  = 17197120;  // u16[128][24]
static const size_t OFF_IMGV  = 17198656;  // u16[16][136]
static const size_t OFF_ZQK   = 17199744;  // u64[4096][256][4]
static const size_t OFF_ZQE   = 25588352;
static const size_t OFF_ZKE   = 33976960;
// transients (dead before pass2<1> writes attn/attne):
static const size_t OFF_XTH = OFF_ATTN;               // bf16[16384][256]
static const size_t OFF_WH  = OFF_ATTN + 4194304;     // bf16[512][256]
static const size_t OFF_WL  = OFF_ATTN + 4259840;     // bf16[512][256]

// ---------------- Kernel 0: prep (x transpose | w split | rel_emb images) ----------------
__global__ __launch_bounds__(256) void k_prep(const float* __restrict__ x,
                                              const float* __restrict__ w,
                                              const float* __restrict__ remb,
                                              unsigned short* __restrict__ xTh,
                                              unsigned short* __restrict__ wh,
                                              unsigned short* __restrict__ wl,
                                              unsigned short* __restrict__ imgQK,
                                              unsigned short* __restrict__ imgV)
{
    const int bid = blockIdx.x;
    const int tid = threadIdx.x;
    if (bid < 256) {           // ---- split+transpose x
        __shared__ unsigned short xs[64*264];
        const int n = bid;
        const int b = n >> 6, h = n & 63;
        const float* xbase = x + (size_t)b*256*4096 + (size_t)h*64;
        const int iw = tid >> 2, cch = (tid & 3) * 64;
        const size_t row = (size_t)n*64 + iw;
        {
            const int c = tid;
            #pragma unroll 4
            for (int ic = 0; ic < 16; ++ic) {
                const float4 v = *(const float4*)&xbase[(size_t)c*4096 + ic*4];
                const float vv[4] = {v.x, v.y, v.z, v.w};
                #pragma unroll
                for (int u = 0; u < 4; ++u) xs[(ic*4+u)*264 + c] = f2bf(vv[u]);
            }
        }
        __syncthreads();
        #pragma unroll
        for (int u8 = 0; u8 < 8; ++u8)
            *(s16x8*)&xTh[row*256 + cch + u8*8] = *(const s16x8*)&xs[iw*264 + cch + u8*8];
        return;
    }
    if (bid < 384) {           // ---- split w
        const int t4 = (bid - 256)*256 + tid;
        const float4 v = *(const float4*)&w[(size_t)t4*4];
        const float vv[4] = {v.x, v.y, v.z, v.w};
        ushort4 hi4, lo4;
        unsigned short* hp = (unsigned short*)&hi4;
        unsigned short* lp = (unsigned short*)&lo4;
        #pragma unroll
        for (int u = 0; u < 4; ++u) {
            hp[u] = f2bf(vv[u]);
            lp[u] = f2bf(vv[u] - bf2f(hp[u]));
        }
        *(ushort4*)&wh[(size_t)t4*4] = hi4;
        *(ushort4*)&wl[(size_t)t4*4] = lo4;
        return;
    }
    // bid == 384: rel_emb images
    if (tid < 128) {
        const int d = tid;
        u64 q0 = 0, q1 = 0, k0 = 0, k1 = 0;
        if (d < 127) {
            #pragma unroll
            for (int c = 0; c < 4; ++c) q0 |= (u64)f2bf(remb[c*127 + d])      << (16*c);
            #pragma unroll
            for (int c = 0; c < 4; ++c) q1 |= (u64)f2bf(remb[(4+c)*127 + d])  << (16*c);
            #pragma unroll
            for (int c = 0; c < 4; ++c) k0 |= (u64)f2bf(remb[(8+c)*127 + d])  << (16*c);
            #pragma unroll
            for (int c = 0; c < 4; ++c) k1 |= (u64)f2bf(remb[(12+c)*127 + d]) << (16*c);
        }
        u64* row = (u64*)(imgQK + (size_t)d*24);
        row[0] = q0; row[1] = q1; row[2] = k0; row[3] = k1; row[4] = 0; row[5] = 0;
    } else {
        for (int e = tid - 128; e < 2176; e += 128) {
            const int cv = e / 136, dd = e - cv*136;
            imgV[e] = (dd < 127) ? f2bf(remb[(16+cv)*127 + dd]) : (unsigned short)0;
        }
    }
}

// ---------------- Kernel 1: qkv(bf16) = (wh+wl).xh via MFMA + bn1 partials (no atomics) ----------------
__global__ __launch_bounds__(512) void k_qkv_mfma(const unsigned short* __restrict__ wh,
                                                  const unsigned short* __restrict__ wl,
                                                  const unsigned short* __restrict__ xTh,
                                                  unsigned short* __restrict__ qkvb,
                                                  float* __restrict__ p1g)
{
    __shared__ char smraw[34816];
    unsigned short* const Ah = (unsigned short*)smraw;           // [128][40]
    unsigned short* const Al = Ah + 5120;
    unsigned short* const Bh = Al + 5120;
    unsigned short* const Cl = (unsigned short*)smraw;           // [128][136] overlay
    float* const part = (float*)(smraw + 20480);                 // [4][128][2] overlay on Bh
    const int o0   = blockIdx.x * 128;
    const int col0 = blockIdx.y * 128;
    const int tid = threadIdx.x;
    const int w = tid >> 6, l = tid & 63, lb = l & 15, h = l >> 4;
    const int oq = (w >> 2) * 64, cq = (w & 3) * 32;

    f32x4 acc[4][2];
    #pragma unroll
    for (int m = 0; m < 4; ++m)
        #pragma unroll
        for (int nn = 0; nn < 2; ++nn) { acc[m][nn][0]=0.f; acc[m][nn][1]=0.f; acc[m][nn][2]=0.f; acc[m][nn][3]=0.f; }

    const int srow = tid >> 2, sc8 = (tid & 3) * 8;
    int4 rA, rL, rB;
    rA = *(const int4*)(wh  + (size_t)(o0  +srow)*256 + sc8);
    rL = *(const int4*)(wl  + (size_t)(o0  +srow)*256 + sc8);
    rB = *(const int4*)(xTh + (size_t)(col0+srow)*256 + sc8);
    *(int4*)&Ah[srow*40 + sc8] = rA;
    *(int4*)&Al[srow*40 + sc8] = rL;
    *(int4*)&Bh[srow*40 + sc8] = rB;

    for (int step = 0; step < 8; ++step) {
        __syncthreads();
        if (step < 7) {
            const int kk = (step+1)*32;
            rA = *(const int4*)(wh  + (size_t)(o0  +srow)*256 + kk + sc8);
            rL = *(const int4*)(wl  + (size_t)(o0  +srow)*256 + kk + sc8);
            rB = *(const int4*)(xTh + (size_t)(col0+srow)*256 + kk + sc8);
        }
        s16x8 ah[4], al[4], bf[2];
        #pragma unroll
        for (int m = 0; m < 4; ++m)  ah[m] = *(const s16x8*)&Ah[(oq + m*16 + lb)*40 + h*8];
        #pragma unroll
        for (int m = 0; m < 4; ++m)  al[m] = *(const s16x8*)&Al[(oq + m*16 + lb)*40 + h*8];
        #pragma unroll
        for (int nn = 0; nn < 2; ++nn) bf[nn] = *(const s16x8*)&Bh[(cq + nn*16 + lb)*40 + h*8];
        #pragma unroll
        for (int m = 0; m < 4; ++m)
            #pragma unroll
            for (int nn = 0; nn < 2; ++nn) {
                acc[m][nn] = __builtin_amdgcn_mfma_f32_16x16x32_bf16(ah[m], bf[nn], acc[m][nn], 0,0,0);
                acc[m][nn] = __builtin_amdgcn_mfma_f32_16x16x32_bf16(al[m], bf[nn], acc[m][nn], 0,0,0);
            }
        __syncthreads();
        if (step < 7) {
            *(int4*)&Ah[srow*40 + sc8] = rA;
            *(int4*)&Al[srow*40 + sc8] = rL;
            *(int4*)&Bh[srow*40 + sc8] = rB;
        }
    }

    // ---- bn1 partials: shfl-reduce over lb, single-writer LDS slots, no atomics
    #pragma unroll
    for (int m = 0; m < 4; ++m)
        #pragma unroll
        for (int r = 0; r < 4; ++r) {
            float s  = acc[m][0][r] + acc[m][1][r];
            float s2 = acc[m][0][r]*acc[m][0][r] + acc[m][1][r]*acc[m][1][r];
            #pragma unroll
            for (int mk = 1; mk < 16; mk <<= 1) { s += __shfl_xor(s, mk); s2 += __shfl_xor(s2, mk); }
            if (lb == 0) {
                const int ol = oq + m*16 + h*4 + r;
                part[((w & 3)*128 + ol)*2 + 0] = s;
                part[((w & 3)*128 + ol)*2 + 1] = s2;
            }
        }
    __syncthreads();
    if (tid < 256) {
        const float v = part[tid] + part[256 + tid] + part[512 + tid] + part[768 + tid];
        p1g[((size_t)blockIdx.y*512 + o0)*2 + tid] = v;
    }
    __syncthreads();   // part reads done before Cl overlay

    #pragma unroll
    for (int m = 0; m < 4; ++m)
        #pragma unroll
        for (int nn = 0; nn < 2; ++nn)
            #pragma unroll
            for (int r = 0; r < 4; ++r)
                Cl[(oq + m*16 + h*4 + r)*136 + cq + nn*16 + lb] = f2bf(acc[m][nn][r]);
    __syncthreads();
    const int erow = tid >> 2, eseg = (tid & 3) * 16;
    #pragma unroll
    for (int h2 = 0; h2 < 2; ++h2) {
        unsigned short* dst = qkvb + ((size_t)((col0 >> 6) + h2)*512 + (o0 + erow))*64 + eseg;
        *(s16x8*)&dst[0] = *(const s16x8*)&Cl[erow*136 + h2*64 + eseg];
        *(s16x8*)&dst[8] = *(const s16x8*)&Cl[erow*136 + h2*64 + eseg + 8];
    }
}

// ---------------- Kernel 2: bn1 finalize (PARALLEL: 512 blocks x 128 thr) ----------------
__global__ __launch_bounds__(128) void k_bn1fin(const float* __restrict__ p1g,
                                                const float* __restrict__ gamma,
                                                const float* __restrict__ beta,
                                                float* __restrict__ a1, float* __restrict__ b1)
{
    const int o = blockIdx.x;          // 0..511
    const int by = threadIdx.x;        // 0..127
    float s  = p1g[((size_t)by*512 + o)*2];
    float s2 = p1g[((size_t)by*512 + o)*2 + 1];
    #pragma unroll
    for (int off = 32; off; off >>= 1) { s += __shfl_down(s, off); s2 += __shfl_down(s2, off); }
    __shared__ float rs[2], rs2[2];
    if ((by & 63) == 0) { rs[by>>6] = s; rs2[by>>6] = s2; }
    __syncthreads();
    if (by == 0) {
        const float S = rs[0] + rs[1], S2 = rs2[0] + rs2[1];
        const float mean = S * (1.f/16384.f);
        const float var  = S2 * (1.f/16384.f) - mean*mean;
        const float A = gamma[o] * rsqrtf(var + 1e-5f);
        a1[o] = A;
        b1[o] = beta[o] - mean*A;
    }
}

// ---------------- Kernels 3/5: per-(n,g) core ----------------
template<int PASSB>
__global__ __launch_bounds__(256) void k_pass2(const unsigned short* __restrict__ qkvb,
    const float* __restrict__ a1, const float* __restrict__ b1,
    const unsigned short* __restrict__ imgQK, const unsigned short* __restrict__ imgV,
    float* __restrict__ p2, const float* __restrict__ a2,
    u64* __restrict__ zqk, u64* __restrict__ zqe, u64* __restrict__ zke,
    unsigned short* __restrict__ attnb, unsigned short* __restrict__ attneb,
    float* __restrict__ p3g)
{
    extern __shared__ char sm[];
    const int bx = blockIdx.x, n = bx >> 4, g = bx & 15;
    const int tid = threadIdx.x;
    const int w = tid >> 6, l = tid & 63, lb = l & 15, h = l >> 4;
    const int i0 = w*16;
    const size_t bbase = ((size_t)bx*256 + tid)*4;
    const s16x8 z8 = {0,0,0,0,0,0,0,0};

    if (!PASSB) {
        unsigned short* const qkT    = (unsigned short*)sm;            // [64][16]
        unsigned short* const rembQK = (unsigned short*)(sm + 2048);   // [128][24]
        unsigned short (* const qeT)[72] = (unsigned short(*)[72])(sm + 8192);
        unsigned short (* const keT)[72] = (unsigned short(*)[72])(sm + 17408);
        float* const red = (float*)(sm + 26624);

        {
            const int4* gsrc = (const int4*)imgQK;
            int4* ldst = (int4*)rembQK;
            for (int t = tid; t < 384; t += 256) ldst[t] = gsrc[t];
        }
        {
            const int a = tid & 63, c0 = (tid >> 6) * 4;
            u64 pk = 0;
            #pragma unroll
            for (int u = 0; u < 4; ++u) {
                const int o = g*32 + c0 + u;
                const float val = a1[o] * bf2f(qkvb[((size_t)n*512 + o)*64 + a]) + b1[o];
                pk |= (u64)f2bf(val) << (16*u);
            }
            *(u64*)&qkT[a*16 + c0] = pk;
        }
        __syncthreads();

        float sqe=0.f, s2qe=0.f, ske=0.f, s2ke=0.f;
        {
            const int a0 = w*16;
            const s16x8 afr = (h < 2) ? *(const s16x8*)&qkT[(a0 + lb)*16 + h*8] : z8;
            #pragma unroll
            for (int dt = 0; dt < 8; ++dt) {
                const int dd = dt*16 + lb;
                const s16x8 bq = (h == 0) ? *(const s16x8*)&rembQK[dd*24 + 0] : z8;
                const s16x8 bk = (h == 1) ? *(const s16x8*)&rembQK[dd*24 + 8] : z8;
                f32x4 zz = {0.f,0.f,0.f,0.f};
                f32x4 cqf = __builtin_amdgcn_mfma_f32_16x16x32_bf16(afr, bq, zz, 0,0,0);
                f32x4 ckf = __builtin_amdgcn_mfma_f32_16x16x32_bf16(afr, bk, zz, 0,0,0);
                #pragma unroll
                for (int r = 0; r < 4; ++r) {
                    const int a = a0 + h*4 + r;
                    const int i = a + 63 - dd;
                    if (i >= 0 && i < 64) {
                        const float vq = cqf[r], vk = ckf[r];
                        qeT[i][a] = f2bf(vq);
                        keT[i][a] = f2bf(vk);
                        sqe += vq; s2qe += vq*vq; ske += vk; s2ke += vk*vk;
                    }
                }
            }
        }
        __syncthreads();

        f32x4 acc[4];
        #pragma unroll
        for (int jt = 0; jt < 4; ++jt) { acc[jt][0]=0.f; acc[jt][1]=0.f; acc[jt][2]=0.f; acc[jt][3]=0.f; }
        #pragma unroll
        for (int kc = 0; kc < 2; ++kc) {
            const s16x8 aq = *(const s16x8*)&qeT[i0 + lb][kc*32 + h*8];
            #pragma unroll
            for (int jt = 0; jt < 4; ++jt) {
                const s16x8 bk2 = *(const s16x8*)&keT[jt*16 + lb][kc*32 + h*8];
                acc[jt] = __builtin_amdgcn_mfma_f32_16x16x32_bf16(aq, bk2, acc[jt], 0,0,0);
            }
        }

        float sqk=0.f, s2qk=0.f;
        #pragma unroll
        for (int jt = 0; jt < 4; ++jt) {
            const u64 q4 = *(const u64*)&qeT[jt*16 + lb][i0 + 4*h];
            const u64 k4 = *(const u64*)&keT[jt*16 + lb][i0 + 4*h];
            zqe[bbase + jt] = q4;
            zke[bbase + jt] = k4;
            u64 pk = 0;
            #pragma unroll
            for (int r = 0; r < 4; ++r) {
                const float q_ = acc[jt][r];
                sqk += q_; s2qk += q_*q_;
                pk |= (u64)f2bf(q_) << (16*r);
            }
            zqk[bbase + jt] = pk;
        }

        float vals[6] = {sqk, s2qk, sqe, s2qe, ske, s2ke};
        #pragma unroll
        for (int q = 0; q < 6; ++q) {
            float v = vals[q];
            #pragma unroll
            for (int off = 32; off; off >>= 1) v += __shfl_xor(v, off);
            if (l == 0) red[w*6 + q] = v;
        }
        __syncthreads();
        if (tid < 6) p2[(size_t)bx*6 + tid] = red[tid] + red[6+tid] + red[12+tid] + red[18+tid];
        return;
    }

    // ================= PASS B =================
    unsigned short (* const PSt)[136]   = (unsigned short(*)[136])(sm);
    unsigned short (* const pT)[72]     = (unsigned short(*)[72])(sm + 17408);
    unsigned short (* const rembV)[136] = (unsigned short(*)[136])(sm + 26624);
    unsigned short (* const vbL)[72]    = (unsigned short(*)[72])(sm + 30976);
    float* const part3 = (float*)sm;    // [4][16][4] overlay (used after final barrier)

    {
        int4 z4i; z4i.x=z4i.y=z4i.z=z4i.w=0;
        int4* dst = (int4*)sm;
        for (int t = tid; t < 1088; t += 256) dst[t] = z4i;
    }
    {
        const int4* gsrc = (const int4*)imgV;
        int4* ldst = (int4*)rembV;
        for (int t = tid; t < 272; t += 256) ldst[t] = gsrc[t];
    }
    {
        const int cv = tid >> 4, ap = (tid & 15) * 4;
        const int o = g*32 + 16 + cv;
        const float A = a1[o], Bc = b1[o];
        const ushort4 vv = *(const ushort4*)&qkvb[((size_t)n*512 + o)*64 + ap];
        u64 pk = 0;
        pk |= (u64)f2bf(A*bf2f(vv.x) + Bc);
        pk |= (u64)f2bf(A*bf2f(vv.y) + Bc) << 16;
        pk |= (u64)f2bf(A*bf2f(vv.z) + Bc) << 32;
        pk |= (u64)f2bf(A*bf2f(vv.w) + Bc) << 48;
        *(u64*)&vbL[cv][ap] = pk;
    }

    const float c_qk = a2[g], c_qe = a2[16+g], c_ke = a2[32+g];
    float p[4][4];
    #pragma unroll
    for (int jt = 0; jt < 4; ++jt) {
        const u64 zq = zqk[bbase + jt];
        const u64 q4 = zqe[bbase + jt];
        const u64 k4 = zke[bbase + jt];
        #pragma unroll
        for (int r = 0; r < 4; ++r) {
            p[jt][r] = c_qk*bf2f((unsigned short)(zq >> (16*r)))
                     + c_qe*bf2f((unsigned short)(q4 >> (16*r)))
                     + c_ke*bf2f((unsigned short)(k4 >> (16*r)));
        }
    }
    #pragma unroll
    for (int r = 0; r < 4; ++r) {
        float m = fmaxf(fmaxf(p[0][r], p[1][r]), fmaxf(p[2][r], p[3][r]));
        #pragma unroll
        for (int mk = 8; mk; mk >>= 1) m = fmaxf(m, __shfl_xor(m, mk));
        float s = 0.f;
        #pragma unroll
        for (int jt = 0; jt < 4; ++jt) { p[jt][r] = __expf(p[jt][r] - m); s += p[jt][r]; }
        #pragma unroll
        for (int mk = 8; mk; mk >>= 1) s += __shfl_xor(s, mk);
        const float inv = 1.f / s;
        #pragma unroll
        for (int jt = 0; jt < 4; ++jt) p[jt][r] *= inv;
    }
    __syncthreads();

    #pragma unroll
    for (int jt = 0; jt < 4; ++jt)
        #pragma unroll
        for (int r = 0; r < 4; ++r) {
            const int i = i0 + 4*h + r, j = jt*16 + lb;
            const unsigned short pb = f2bf(p[jt][r]);
            pT[i][j] = pb;
            PSt[i][i + 63 - j] = pb;
        }
    __syncthreads();

    f32x4 accA = {0.f,0.f,0.f,0.f}, accE = {0.f,0.f,0.f,0.f};
    #pragma unroll
    for (int kc = 0; kc < 2; ++kc) {
        const s16x8 av = *(const s16x8*)&vbL[lb][kc*32 + h*8];
        const s16x8 bp = *(const s16x8*)&pT[i0 + lb][kc*32 + h*8];
        accA = __builtin_amdgcn_mfma_f32_16x16x32_bf16(av, bp, accA, 0,0,0);
    }
    #pragma unroll
    for (int kc = 0; kc < 4; ++kc) {
        const s16x8 ae = *(const s16x8*)&rembV[lb][kc*32 + h*8];
        const s16x8 bs = *(const s16x8*)&PSt[i0 + lb][kc*32 + h*8];
        accE = __builtin_amdgcn_mfma_f32_16x16x32_bf16(ae, bs, accE, 0,0,0);
    }
    unsigned short* aw = attnb  + ((size_t)n*16 + g)*1024;
    unsigned short* ew = attneb + ((size_t)n*16 + g)*1024;
    #pragma unroll
    for (int r = 0; r < 4; ++r) {
        aw[(4*h + r)*64 + i0 + lb] = f2bf(accA[r]);
        ew[(4*h + r)*64 + i0 + lb] = f2bf(accE[r]);
    }

    // ---- bn3 partials: shfl-reduce over lb (i), single-writer LDS, no atomics
    __syncthreads();   // all LDS reads (MFMA operands) complete before overlay
    #pragma unroll
    for (int r = 0; r < 4; ++r) {
        float sA = accA[r], sA2 = accA[r]*accA[r];
        float sE = accE[r], sE2 = accE[r]*accE[r];
        #pragma unroll
        for (int mk = 1; mk < 16; mk <<= 1) {
            sA += __shfl_xor(sA, mk); sA2 += __shfl_xor(sA2, mk);
            sE += __shfl_xor(sE, mk); sE2 += __shfl_xor(sE2, mk);
        }
        if (lb == 0) {
            const int c = 4*h + r;
            float* dst = part3 + ((w*16 + c) * 4);
            dst[0] = sA; dst[1] = sA2; dst[2] = sE; dst[3] = sE2;
        }
    }
    __syncthreads();
    if (tid < 64) {
        const float v = part3[tid] + part3[64 + tid] + part3[128 + tid] + part3[192 + tid];
        p3g[(size_t)bx*64 + tid] = v;
    }
}

// ---------------- Kernel 4: bn2 finalize ----------------
__global__ __launch_bounds__(256) void k_bn2(const float* __restrict__ p2,
                                             const float* __restrict__ gamma2,
                                             float* __restrict__ a2)
{
    const int ch = blockIdx.x*4 + (threadIdx.x >> 6);
    const int l = threadIdx.x & 63;
    const int kind = ch >> 4, g = ch & 15;
    float s = 0.f, s2 = 0.f;
    #pragma unroll
    for (int q = 0; q < 4; ++q) {
        const int nn = q*64 + l;
        const float* p = p2 + ((size_t)nn*16 + g)*6 + 2*kind;
        s += p[0]; s2 += p[1];
    }
    #pragma unroll
    for (int off = 32; off; off >>= 1) { s += __shfl_down(s, off); s2 += __shfl_down(s2, off); }
    if (l == 0) {
        const float mean = s * (1.f/1048576.f);
        const float var  = s2 * (1.f/1048576.f) - mean*mean;
        a2[ch] = gamma2[ch] * rsqrtf(var + 1e-5f);
    }
}

// ---------------- Kernel 6: bn3 finalize (PARALLEL: 512 blocks x 256 thr) ----------------
__global__ __launch_bounds__(256) void k_bn3fin(const float* __restrict__ p3g,
                                                const float* __restrict__ gamma,
                                                const float* __restrict__ beta,
                                                float* __restrict__ a3, float* __restrict__ b3)
{
    const int o = blockIdx.x;          // 0..511
    const int g = o >> 5, rem = o & 31, c = rem >> 1, sflag = rem & 1;
    const int base = c*4 + sflag*2;
    const int nn = threadIdx.x;        // 0..255
    const float* p = p3g + ((size_t)nn*16 + g)*64 + base;
    float s = p[0], s2 = p[1];
    #pragma unroll
    for (int off = 32; off; off >>= 1) { s += __shfl_down(s, off); s2 += __shfl_down(s2, off); }
    __shared__ float rs[4], rs2[4];
    if ((nn & 63) == 0) { rs[nn>>6] = s; rs2[nn>>6] = s2; }
    __syncthreads();
    if (nn == 0) {
        const float S  = rs[0]+rs[1]+rs[2]+rs[3];
        const float S2 = rs2[0]+rs2[1]+rs2[2]+rs2[3];
        const float mean = S * (1.f/16384.f);
        const float var  = S2 * (1.f/16384.f) - mean*mean;
        const float A = gamma[o] * rsqrtf(var + 1e-5f);
        a3[o] = A;
        b3[o] = beta[o] - mean*A;
    }
}

// ---------------- Kernel 7: apply bn3, sum channel pairs, transpose (float4) ----------------
__global__ __launch_bounds__(256) void k_out(const unsigned short* __restrict__ attnb,
                                             const unsigned short* __restrict__ attneb,
                                             const float* __restrict__ a3,
                                             const float* __restrict__ b3,
                                             float* __restrict__ out)
{
    const int idx4 = blockIdx.x*256 + threadIdx.x;
    const int i4 = (idx4 & 15) * 4;
    const int h  = (idx4 >> 4) & 63;
    const int oc = (idx4 >> 10) & 255;
    const int b  = idx4 >> 18;
    const int g = oc >> 4, c = oc & 15;
    const int n = b*64 + h;
    const size_t src = ((size_t)n*16 + g)*1024 + (size_t)c*64 + i4;
    const int o0 = g*32 + 2*c;
    const float A0 = a3[o0], A1 = a3[o0+1], Bc = b3[o0] + b3[o0+1];
    const ushort4 va = *(const ushort4*)&attnb[src];
    const ushort4 ve = *(const ushort4*)&attneb[src];
    float4 o4;
    o4.x = A0*bf2f(va.x) + A1*bf2f(ve.x) + Bc;
    o4.y = A0*bf2f(va.y) + A1*bf2f(ve.y) + Bc;
    o4.z = A0*bf2f(va.z) + A1*bf2f(ve.z) + Bc;
    o4.w = A0*bf2f(va.w) + A1*bf2f(ve.w) + Bc;
    *(float4*)&out[((size_t)b*256 + oc)*4096 + h*64 + i4] = o4;
}

extern "C" void kernel_launch(void* const* d_in, const int* in_sizes, int n_in,
                              void* d_out, int out_size, void* d_ws, size_t ws_size,
                              hipStream_t stream) {
    const float* x    = (const float*)d_in[0];
    const float* w    = (const float*)d_in[1];
    const float* g1   = (const float*)d_in[2];
    const float* be1  = (const float*)d_in[3];
    const float* remb = (const float*)d_in[4];
    const float* g2   = (const float*)d_in[5];
    const float* g3   = (const float*)d_in[7];
    const float* be3  = (const float*)d_in[8];
    float* out = (float*)d_out;
    float* ws  = (float*)d_ws;

    unsigned short* qkvb  = (unsigned short*)(ws + OFF_QKV);
    float* a1    = ws + OFF_A1;
    float* b1    = ws + OFF_B1;
    float* p2    = ws + OFF_P2;
    float* a2    = ws + OFF_A2;
    unsigned short* attnb  = (unsigned short*)(ws + OFF_ATTN);
    unsigned short* attneb = (unsigned short*)(ws + OFF_ATTNE);
    float* a3    = ws + OFF_A3;
    float* b3    = ws + OFF_B3;
    float* p1g   = ws + OFF_P1G;
    float* p3g   = ws + OFF_P3G;
    unsigned short* imgQK = (unsigned short*)(ws + OFF_IMGQ);
    unsigned short* imgV  = (unsigned short*)(ws + OFF_IMGV);
    u64* zqk = (u64*)(ws + OFF_ZQK);
    u64* zqe = (u64*)(ws + OFF_ZQE);
    u64* zke = (u64*)(ws + OFF_ZKE);
    unsigned short* xTh = (unsigned short*)(ws + OFF_XTH);
    unsigned short* wh  = (unsigned short*)(ws + OFF_WH);
    unsigned short* wl  = (unsigned short*)(ws + OFF_WL);

    const int SHM_A = 26720;
    const int SHM_B = 33280;
    k_prep<<<385, 256, 0, stream>>>(x, w, remb, xTh, wh, wl, imgQK, imgV);
    k_qkv_mfma<<<dim3(4, 128), 512, 0, stream>>>(wh, wl, xTh, qkvb, p1g);
    k_bn1fin<<<512, 128, 0, stream>>>(p1g, g1, be1, a1, b1);
    k_pass2<0><<<4096, 256, SHM_A, stream>>>(qkvb, a1, b1, imgQK, imgV, p2, nullptr, zqk, zqe, zke, nullptr, nullptr, nullptr);
    k_bn2<<<12, 256, 0, stream>>>(p2, g2, a2);
    k_pass2<1><<<4096, 256, SHM_B, stream>>>(qkvb, a1, b1, imgQK, imgV, nullptr, a2, zqk, zqe, zke, attnb, attneb, p3g);
    k_bn3fin<<<512, 256, 0, stream>>>(p3g, g3, be3, a3, b3);
    k_out<<<4096, 256, 0, stream>>>(attnb, attneb, a3, b3, out);
}

// Round 15
// 106.820 us; speedup vs baseline: 1.1673x; 1.0672x over previous
//
#include <hip/hip_runtime.h>
#include <hip/hip_bf16.h>

typedef short s16x8 __attribute__((ext_vector_type(8)));
typedef float f32x4 __attribute__((ext_vector_type(4)));
typedef unsigned long long u64;

static __device__ __forceinline__ unsigned short f2bf(float f){
    unsigned int u = __float_as_uint(f);
    u += 0x7fffu + ((u >> 16) & 1u);
    return (unsigned short)(u >> 16);
}
static __device__ __forceinline__ float bf2f(unsigned short h){
    return __uint_as_float(((unsigned int)h) << 16);
}

// ---------------- workspace layout (float offsets) ----------------
static const size_t OFF_QKV   = 0;         // bf16[256][512][64]
static const size_t OFF_A1    = 8388608;
static const size_t OFF_B1    = 8389120;
static const size_t OFF_P2    = 8389632;
static const size_t OFF_ATTN  = 8414272;   // bf16[256][16][16][64]
static const size_t OFF_ATTNE = 12608576;  // bf16[256][16][16][64]
static const size_t OFF_A3    = 16802880;
static const size_t OFF_B3    = 16803392;
static const size_t OFF_IMGQ  = 16803904;  // u16[128][24]
static const size_t OFF_IMGV  = 16805440;  // u16[16][136]
static const size_t OFF_ZQK   = 16806528;  // u64[4096][256][4]
static const size_t OFF_ZQE   = 25195136;
static const size_t OFF_ZKE   = 33583744;
// transients (dead before pass2<1> writes attn/attne):
static const size_t OFF_XTH = OFF_ATTN;               // bf16[16384][256]
static const size_t OFF_WH  = OFF_ATTN + 4194304;     // bf16[512][256]
static const size_t OFF_WL  = OFF_ATTN + 4259840;     // bf16[512][256]

// ---------------- Kernel 0: prep (x transpose | w split | rel_emb images) ----------------
__global__ __launch_bounds__(256) void k_prep(const float* __restrict__ x,
                                              const float* __restrict__ w,
                                              const float* __restrict__ remb,
                                              unsigned short* __restrict__ xTh,
                                              unsigned short* __restrict__ wh,
                                              unsigned short* __restrict__ wl,
                                              unsigned short* __restrict__ imgQK,
                                              unsigned short* __restrict__ imgV)
{
    const int bid = blockIdx.x;
    const int tid = threadIdx.x;
    if (bid < 256) {           // ---- split+transpose x
        __shared__ unsigned short xs[64*264];
        const int n = bid;
        const int b = n >> 6, h = n & 63;
        const float* xbase = x + (size_t)b*256*4096 + (size_t)h*64;
        const int iw = tid >> 2, cch = (tid & 3) * 64;
        const size_t row = (size_t)n*64 + iw;
        {
            const int c = tid;
            #pragma unroll 4
            for (int ic = 0; ic < 16; ++ic) {
                const float4 v = *(const float4*)&xbase[(size_t)c*4096 + ic*4];
                const float vv[4] = {v.x, v.y, v.z, v.w};
                #pragma unroll
                for (int u = 0; u < 4; ++u) xs[(ic*4+u)*264 + c] = f2bf(vv[u]);
            }
        }
        __syncthreads();
        #pragma unroll
        for (int u8 = 0; u8 < 8; ++u8)
            *(s16x8*)&xTh[row*256 + cch + u8*8] = *(const s16x8*)&xs[iw*264 + cch + u8*8];
        return;
    }
    if (bid < 384) {           // ---- split w
        const int t4 = (bid - 256)*256 + tid;
        const float4 v = *(const float4*)&w[(size_t)t4*4];
        const float vv[4] = {v.x, v.y, v.z, v.w};
        ushort4 hi4, lo4;
        unsigned short* hp = (unsigned short*)&hi4;
        unsigned short* lp = (unsigned short*)&lo4;
        #pragma unroll
        for (int u = 0; u < 4; ++u) {
            hp[u] = f2bf(vv[u]);
            lp[u] = f2bf(vv[u] - bf2f(hp[u]));
        }
        *(ushort4*)&wh[(size_t)t4*4] = hi4;
        *(ushort4*)&wl[(size_t)t4*4] = lo4;
        return;
    }
    // bid == 384: rel_emb images
    if (tid < 128) {
        const int d = tid;
        u64 q0 = 0, q1 = 0, k0 = 0, k1 = 0;
        if (d < 127) {
            #pragma unroll
            for (int c = 0; c < 4; ++c) q0 |= (u64)f2bf(remb[c*127 + d])      << (16*c);
            #pragma unroll
            for (int c = 0; c < 4; ++c) q1 |= (u64)f2bf(remb[(4+c)*127 + d])  << (16*c);
            #pragma unroll
            for (int c = 0; c < 4; ++c) k0 |= (u64)f2bf(remb[(8+c)*127 + d])  << (16*c);
            #pragma unroll
            for (int c = 0; c < 4; ++c) k1 |= (u64)f2bf(remb[(12+c)*127 + d]) << (16*c);
        }
        u64* row = (u64*)(imgQK + (size_t)d*24);
        row[0] = q0; row[1] = q1; row[2] = k0; row[3] = k1; row[4] = 0; row[5] = 0;
    } else {
        for (int e = tid - 128; e < 2176; e += 128) {
            const int cv = e / 136, dd = e - cv*136;
            imgV[e] = (dd < 127) ? f2bf(remb[(16+cv)*127 + dd]) : (unsigned short)0;
        }
    }
}

// ---------------- Kernel 1: qkv(bf16) = (wh+wl).xh via MFMA (round-9/12 verified) ----------------
__global__ __launch_bounds__(512) void k_qkv_mfma(const unsigned short* __restrict__ wh,
                                                  const unsigned short* __restrict__ wl,
                                                  const unsigned short* __restrict__ xTh,
                                                  unsigned short* __restrict__ qkvb)
{
    __shared__ char smraw[34816];
    unsigned short* const Ah = (unsigned short*)smraw;           // [128][40]
    unsigned short* const Al = Ah + 5120;
    unsigned short* const Bh = Al + 5120;
    unsigned short* const Cl = (unsigned short*)smraw;           // [128][136] overlay
    const int o0   = blockIdx.x * 128;
    const int col0 = blockIdx.y * 128;
    const int tid = threadIdx.x;
    const int w = tid >> 6, l = tid & 63, lb = l & 15, h = l >> 4;
    const int oq = (w >> 2) * 64, cq = (w & 3) * 32;

    f32x4 acc[4][2];
    #pragma unroll
    for (int m = 0; m < 4; ++m)
        #pragma unroll
        for (int nn = 0; nn < 2; ++nn) { acc[m][nn][0]=0.f; acc[m][nn][1]=0.f; acc[m][nn][2]=0.f; acc[m][nn][3]=0.f; }

    const int srow = tid >> 2, sc8 = (tid & 3) * 8;
    int4 rA, rL, rB;
    rA = *(const int4*)(wh  + (size_t)(o0  +srow)*256 + sc8);
    rL = *(const int4*)(wl  + (size_t)(o0  +srow)*256 + sc8);
    rB = *(const int4*)(xTh + (size_t)(col0+srow)*256 + sc8);
    *(int4*)&Ah[srow*40 + sc8] = rA;
    *(int4*)&Al[srow*40 + sc8] = rL;
    *(int4*)&Bh[srow*40 + sc8] = rB;

    for (int step = 0; step < 8; ++step) {
        __syncthreads();
        if (step < 7) {
            const int kk = (step+1)*32;
            rA = *(const int4*)(wh  + (size_t)(o0  +srow)*256 + kk + sc8);
            rL = *(const int4*)(wl  + (size_t)(o0  +srow)*256 + kk + sc8);
            rB = *(const int4*)(xTh + (size_t)(col0+srow)*256 + kk + sc8);
        }
        s16x8 ah[4], al[4], bf[2];
        #pragma unroll
        for (int m = 0; m < 4; ++m)  ah[m] = *(const s16x8*)&Ah[(oq + m*16 + lb)*40 + h*8];
        #pragma unroll
        for (int m = 0; m < 4; ++m)  al[m] = *(const s16x8*)&Al[(oq + m*16 + lb)*40 + h*8];
        #pragma unroll
        for (int nn = 0; nn < 2; ++nn) bf[nn] = *(const s16x8*)&Bh[(cq + nn*16 + lb)*40 + h*8];
        #pragma unroll
        for (int m = 0; m < 4; ++m)
            #pragma unroll
            for (int nn = 0; nn < 2; ++nn) {
                acc[m][nn] = __builtin_amdgcn_mfma_f32_16x16x32_bf16(ah[m], bf[nn], acc[m][nn], 0,0,0);
                acc[m][nn] = __builtin_amdgcn_mfma_f32_16x16x32_bf16(al[m], bf[nn], acc[m][nn], 0,0,0);
            }
        __syncthreads();
        if (step < 7) {
            *(int4*)&Ah[srow*40 + sc8] = rA;
            *(int4*)&Al[srow*40 + sc8] = rL;
            *(int4*)&Bh[srow*40 + sc8] = rB;
        }
    }

    #pragma unroll
    for (int m = 0; m < 4; ++m)
        #pragma unroll
        for (int nn = 0; nn < 2; ++nn)
            #pragma unroll
            for (int r = 0; r < 4; ++r)
                Cl[(oq + m*16 + h*4 + r)*136 + cq + nn*16 + lb] = f2bf(acc[m][nn][r]);
    __syncthreads();
    const int erow = tid >> 2, eseg = (tid & 3) * 16;
    #pragma unroll
    for (int h2 = 0; h2 < 2; ++h2) {
        unsigned short* dst = qkvb + ((size_t)((col0 >> 6) + h2)*512 + (o0 + erow))*64 + eseg;
        *(s16x8*)&dst[0] = *(const s16x8*)&Cl[erow*136 + h2*64 + eseg];
        *(s16x8*)&dst[8] = *(const s16x8*)&Cl[erow*136 + h2*64 + eseg + 8];
    }
}

// ---------------- Kernel 2: bn1 stats (bf16 qkv) -> folded affine a1,b1 ----------------
__global__ __launch_bounds__(256) void k_bn1(const unsigned short* __restrict__ qkvb,
                                             const float* __restrict__ gamma,
                                             const float* __restrict__ beta,
                                             float* __restrict__ a1, float* __restrict__ b1)
{
    const int o = blockIdx.x;
    const int tid = threadIdx.x;
    float s = 0.f, s2 = 0.f;
    for (int t = tid; t < 2048; t += 256) {
        const int n = t >> 3, i8 = (t & 7) * 8;
        const s16x8 v8 = *(const s16x8*)&qkvb[((size_t)n*512 + o)*64 + i8];
        #pragma unroll
        for (int j = 0; j < 8; ++j) {
            const float f = bf2f((unsigned short)v8[j]);
            s += f; s2 += f*f;
        }
    }
    __shared__ float rs[4], rs2[4];
    #pragma unroll
    for (int off = 32; off; off >>= 1) { s += __shfl_down(s, off); s2 += __shfl_down(s2, off); }
    if ((tid & 63) == 0) { rs[tid>>6] = s; rs2[tid>>6] = s2; }
    __syncthreads();
    if (tid == 0) {
        const float S  = rs[0]+rs[1]+rs[2]+rs[3];
        const float S2 = rs2[0]+rs2[1]+rs2[2]+rs2[3];
        const float mean = S * (1.f/16384.f);
        const float var  = S2 * (1.f/16384.f) - mean*mean;
        const float A = gamma[o] * rsqrtf(var + 1e-5f);
        a1[o] = A;
        b1[o] = beta[o] - mean*A;
    }
}

// ---------------- Kernels 3/5: per-(n,g) core. passB computes its own bn2 scales from p2. ----------------
template<int PASSB>
__global__ __launch_bounds__(256) void k_pass2(const unsigned short* __restrict__ qkvb,
    const float* __restrict__ a1, const float* __restrict__ b1,
    const unsigned short* __restrict__ imgQK, const unsigned short* __restrict__ imgV,
    float* __restrict__ p2, const float* __restrict__ gamma2,
    u64* __restrict__ zqk, u64* __restrict__ zqe, u64* __restrict__ zke,
    unsigned short* __restrict__ attnb, unsigned short* __restrict__ attneb)
{
    extern __shared__ char sm[];
    const int bx = blockIdx.x, n = bx >> 4, g = bx & 15;
    const int tid = threadIdx.x;
    const int w = tid >> 6, l = tid & 63, lb = l & 15, h = l >> 4;
    const int i0 = w*16;
    const size_t bbase = ((size_t)bx*256 + tid)*4;
    const s16x8 z8 = {0,0,0,0,0,0,0,0};

    if (!PASSB) {
        unsigned short* const qkT    = (unsigned short*)sm;            // [64][16]
        unsigned short* const rembQK = (unsigned short*)(sm + 2048);   // [128][24]
        unsigned short (* const qeT)[72] = (unsigned short(*)[72])(sm + 8192);
        unsigned short (* const keT)[72] = (unsigned short(*)[72])(sm + 17408);
        float* const red = (float*)(sm + 26624);

        {
            const int4* gsrc = (const int4*)imgQK;
            int4* ldst = (int4*)rembQK;
            for (int t = tid; t < 384; t += 256) ldst[t] = gsrc[t];
        }
        {
            const int a = tid & 63, c0 = (tid >> 6) * 4;
            u64 pk = 0;
            #pragma unroll
            for (int u = 0; u < 4; ++u) {
                const int o = g*32 + c0 + u;
                const float val = a1[o] * bf2f(qkvb[((size_t)n*512 + o)*64 + a]) + b1[o];
                pk |= (u64)f2bf(val) << (16*u);
            }
            *(u64*)&qkT[a*16 + c0] = pk;
        }
        __syncthreads();

        float sqe=0.f, s2qe=0.f, ske=0.f, s2ke=0.f;
        {
            const int a0 = w*16;
            const s16x8 afr = (h < 2) ? *(const s16x8*)&qkT[(a0 + lb)*16 + h*8] : z8;
            #pragma unroll
            for (int dt = 0; dt < 8; ++dt) {
                const int dd = dt*16 + lb;
                const s16x8 bq = (h == 0) ? *(const s16x8*)&rembQK[dd*24 + 0] : z8;
                const s16x8 bk = (h == 1) ? *(const s16x8*)&rembQK[dd*24 + 8] : z8;
                f32x4 zz = {0.f,0.f,0.f,0.f};
                f32x4 cqf = __builtin_amdgcn_mfma_f32_16x16x32_bf16(afr, bq, zz, 0,0,0);
                f32x4 ckf = __builtin_amdgcn_mfma_f32_16x16x32_bf16(afr, bk, zz, 0,0,0);
                #pragma unroll
                for (int r = 0; r < 4; ++r) {
                    const int a = a0 + h*4 + r;
                    const int i = a + 63 - dd;
                    if (i >= 0 && i < 64) {
                        const float vq = cqf[r], vk = ckf[r];
                        qeT[i][a] = f2bf(vq);
                        keT[i][a] = f2bf(vk);
                        sqe += vq; s2qe += vq*vq; ske += vk; s2ke += vk*vk;
                    }
                }
            }
        }
        __syncthreads();

        f32x4 acc[4];
        #pragma unroll
        for (int jt = 0; jt < 4; ++jt) { acc[jt][0]=0.f; acc[jt][1]=0.f; acc[jt][2]=0.f; acc[jt][3]=0.f; }
        #pragma unroll
        for (int kc = 0; kc < 2; ++kc) {
            const s16x8 aq = *(const s16x8*)&qeT[i0 + lb][kc*32 + h*8];
            #pragma unroll
            for (int jt = 0; jt < 4; ++jt) {
                const s16x8 bk2 = *(const s16x8*)&keT[jt*16 + lb][kc*32 + h*8];
                acc[jt] = __builtin_amdgcn_mfma_f32_16x16x32_bf16(aq, bk2, acc[jt], 0,0,0);
            }
        }

        float sqk=0.f, s2qk=0.f;
        #pragma unroll
        for (int jt = 0; jt < 4; ++jt) {
            const u64 q4 = *(const u64*)&qeT[jt*16 + lb][i0 + 4*h];
            const u64 k4 = *(const u64*)&keT[jt*16 + lb][i0 + 4*h];
            zqe[bbase + jt] = q4;
            zke[bbase + jt] = k4;
            u64 pk = 0;
            #pragma unroll
            for (int r = 0; r < 4; ++r) {
                const float q_ = acc[jt][r];
                sqk += q_; s2qk += q_*q_;
                pk |= (u64)f2bf(q_) << (16*r);
            }
            zqk[bbase + jt] = pk;
        }

        float vals[6] = {sqk, s2qk, sqe, s2qe, ske, s2ke};
        #pragma unroll
        for (int q = 0; q < 6; ++q) {
            float v = vals[q];
            #pragma unroll
            for (int off = 32; off; off >>= 1) v += __shfl_xor(v, off);
            if (l == 0) red[w*6 + q] = v;
        }
        __syncthreads();
        if (tid < 6) p2[(size_t)bx*6 + tid] = red[tid] + red[6+tid] + red[12+tid] + red[18+tid];
        return;
    }

    // ================= PASS B =================
    unsigned short (* const PSt)[136]   = (unsigned short(*)[136])(sm);
    unsigned short (* const pT)[72]     = (unsigned short(*)[72])(sm + 17408);
    unsigned short (* const rembV)[136] = (unsigned short(*)[136])(sm + 26624);
    unsigned short (* const vbL)[72]    = (unsigned short(*)[72])(sm + 30976);
    float* const cbuf = (float*)(sm + 33280);   // 3 floats: bn2 scales

    {
        int4 z4i; z4i.x=z4i.y=z4i.z=z4i.w=0;
        int4* dst = (int4*)sm;
        for (int t = tid; t < 1088; t += 256) dst[t] = z4i;
    }
    {
        const int4* gsrc = (const int4*)imgV;
        int4* ldst = (int4*)rembV;
        for (int t = tid; t < 272; t += 256) ldst[t] = gsrc[t];
    }
    {
        const int cv = tid >> 4, ap = (tid & 15) * 4;
        const int o = g*32 + 16 + cv;
        const float A = a1[o], Bc = b1[o];
        const ushort4 vv = *(const ushort4*)&qkvb[((size_t)n*512 + o)*64 + ap];
        u64 pk = 0;
        pk |= (u64)f2bf(A*bf2f(vv.x) + Bc);
        pk |= (u64)f2bf(A*bf2f(vv.y) + Bc) << 16;
        pk |= (u64)f2bf(A*bf2f(vv.z) + Bc) << 32;
        pk |= (u64)f2bf(A*bf2f(vv.w) + Bc) << 48;
        *(u64*)&vbL[cv][ap] = pk;
    }
    // wave 0: per-block bn2 reduction from p2 (96 KB, L2-hot) — replaces the k_bn2 kernel
    if (w == 0) {
        float sv[6] = {0.f,0.f,0.f,0.f,0.f,0.f};
        #pragma unroll
        for (int qd = 0; qd < 4; ++qd) {
            const int nn = l + 64*qd;
            const float* p = p2 + ((size_t)nn*16 + g)*6;
            #pragma unroll
            for (int q = 0; q < 6; ++q) sv[q] += p[q];
        }
        #pragma unroll
        for (int q = 0; q < 6; ++q) {
            #pragma unroll
            for (int off = 32; off; off >>= 1) sv[q] += __shfl_xor(sv[q], off);
        }
        if (l < 3) {
            const float mean = sv[2*l] * (1.f/1048576.f);
            const float var  = sv[2*l+1] * (1.f/1048576.f) - mean*mean;
            cbuf[l] = gamma2[l*16 + g] * rsqrtf(var + 1e-5f);
        }
    }
    __syncthreads();

    const float c_qk = cbuf[0], c_qe = cbuf[1], c_ke = cbuf[2];
    float p[4][4];
    #pragma unroll
    for (int jt = 0; jt < 4; ++jt) {
        const u64 zq = zqk[bbase + jt];
        const u64 q4 = zqe[bbase + jt];
        const u64 k4 = zke[bbase + jt];
        #pragma unroll
        for (int r = 0; r < 4; ++r) {
            p[jt][r] = c_qk*bf2f((unsigned short)(zq >> (16*r)))
                     + c_qe*bf2f((unsigned short)(q4 >> (16*r)))
                     + c_ke*bf2f((unsigned short)(k4 >> (16*r)));
        }
    }
    #pragma unroll
    for (int r = 0; r < 4; ++r) {
        float m = fmaxf(fmaxf(p[0][r], p[1][r]), fmaxf(p[2][r], p[3][r]));
        #pragma unroll
        for (int mk = 8; mk; mk >>= 1) m = fmaxf(m, __shfl_xor(m, mk));
        float s = 0.f;
        #pragma unroll
        for (int jt = 0; jt < 4; ++jt) { p[jt][r] = __expf(p[jt][r] - m); s += p[jt][r]; }
        #pragma unroll
        for (int mk = 8; mk; mk >>= 1) s += __shfl_xor(s, mk);
        const float inv = 1.f / s;
        #pragma unroll
        for (int jt = 0; jt < 4; ++jt) p[jt][r] *= inv;
    }
    __syncthreads();

    #pragma unroll
    for (int jt = 0; jt < 4; ++jt)
        #pragma unroll
        for (int r = 0; r < 4; ++r) {
            const int i = i0 + 4*h + r, j = jt*16 + lb;
            const unsigned short pb = f2bf(p[jt][r]);
            pT[i][j] = pb;
            PSt[i][i + 63 - j] = pb;
        }
    __syncthreads();

    f32x4 accA = {0.f,0.f,0.f,0.f}, accE = {0.f,0.f,0.f,0.f};
    #pragma unroll
    for (int kc = 0; kc < 2; ++kc) {
        const s16x8 av = *(const s16x8*)&vbL[lb][kc*32 + h*8];
        const s16x8 bp = *(const s16x8*)&pT[i0 + lb][kc*32 + h*8];
        accA = __builtin_amdgcn_mfma_f32_16x16x32_bf16(av, bp, accA, 0,0,0);
    }
    #pragma unroll
    for (int kc = 0; kc < 4; ++kc) {
        const s16x8 ae = *(const s16x8*)&rembV[lb][kc*32 + h*8];
        const s16x8 bs = *(const s16x8*)&PSt[i0 + lb][kc*32 + h*8];
        accE = __builtin_amdgcn_mfma_f32_16x16x32_bf16(ae, bs, accE, 0,0,0);
    }
    unsigned short* aw = attnb  + ((size_t)n*16 + g)*1024;
    unsigned short* ew = attneb + ((size_t)n*16 + g)*1024;
    #pragma unroll
    for (int r = 0; r < 4; ++r) {
        aw[(4*h + r)*64 + i0 + lb] = f2bf(accA[r]);
        ew[(4*h + r)*64 + i0 + lb] = f2bf(accE[r]);
    }
}

// ---------------- Kernel 6: bn3 stats (bf16 attn) -> a3,b3 ----------------
__global__ __launch_bounds__(256) void k_bn3(const unsigned short* __restrict__ attnb,
                                             const unsigned short* __restrict__ attneb,
                                             const float* __restrict__ gamma,
                                             const float* __restrict__ beta,
                                             float* __restrict__ a3, float* __restrict__ b3)
{
    const int o = blockIdx.x;
    const int g = o >> 5, rem = o & 31, c = rem >> 1, sflag = rem & 1;
    const unsigned short* src = (sflag ? attneb : attnb) + (size_t)g*1024 + (size_t)c*64;
    const int tid = threadIdx.x;
    float s = 0.f, s2 = 0.f;
    for (int t = tid; t < 2048; t += 256) {
        const int n = t >> 3, i8 = (t & 7) * 8;
        const s16x8 v8 = *(const s16x8*)&src[(size_t)n*16384 + i8];
        #pragma unroll
        for (int j = 0; j < 8; ++j) {
            const float f = bf2f((unsigned short)v8[j]);
            s += f; s2 += f*f;
        }
    }
    __shared__ float rs[4], rs2[4];
    #pragma unroll
    for (int off = 32; off; off >>= 1) { s += __shfl_down(s, off); s2 += __shfl_down(s2, off); }
    if ((tid & 63) == 0) { rs[tid>>6] = s; rs2[tid>>6] = s2; }
    __syncthreads();
    if (tid == 0) {
        const float S  = rs[0]+rs[1]+rs[2]+rs[3];
        const float S2 = rs2[0]+rs2[1]+rs2[2]+rs2[3];
        const float mean = S * (1.f/16384.f);
        const float var  = S2 * (1.f/16384.f) - mean*mean;
        const float A = gamma[o] * rsqrtf(var + 1e-5f);
        a3[o] = A;
        b3[o] = beta[o] - mean*A;
    }
}

// ---------------- Kernel 7: apply bn3, sum channel pairs, transpose (8-wide) ----------------
__global__ __launch_bounds__(256) void k_out(const unsigned short* __restrict__ attnb,
                                             const unsigned short* __restrict__ attneb,
                                             const float* __restrict__ a3,
                                             const float* __restrict__ b3,
                                             float* __restrict__ out)
{
    const int idx8 = blockIdx.x*256 + threadIdx.x;   // 524,288 octets
    const int i8 = (idx8 & 7) * 8;
    const int h  = (idx8 >> 3) & 63;
    const int oc = (idx8 >> 9) & 255;
    const int b  = idx8 >> 17;
    const int g = oc >> 4, c = oc & 15;
    const int n = b*64 + h;
    const size_t src = ((size_t)n*16 + g)*1024 + (size_t)c*64 + i8;
    const int o0 = g*32 + 2*c;
    const float A0 = a3[o0], A1 = a3[o0+1], Bc = b3[o0] + b3[o0+1];
    const s16x8 va = *(const s16x8*)&attnb[src];
    const s16x8 ve = *(const s16x8*)&attneb[src];
    float res[8];
    #pragma unroll
    for (int j = 0; j < 8; ++j)
        res[j] = A0*bf2f((unsigned short)va[j]) + A1*bf2f((unsigned short)ve[j]) + Bc;
    float* dst = &out[((size_t)b*256 + oc)*4096 + h*64 + i8];
    *(float4*)&dst[0] = make_float4(res[0], res[1], res[2], res[3]);
    *(float4*)&dst[4] = make_float4(res[4], res[5], res[6], res[7]);
}

extern "C" void kernel_launch(void* const* d_in, const int* in_sizes, int n_in,
                              void* d_out, int out_size, void* d_ws, size_t ws_size,
                              hipStream_t stream) {
    const float* x    = (const float*)d_in[0];
    const float* w    = (const float*)d_in[1];
    const float* g1   = (const float*)d_in[2];
    const float* be1  = (const float*)d_in[3];
    const float* remb = (const float*)d_in[4];
    const float* g2   = (const float*)d_in[5];
    const float* g3   = (const float*)d_in[7];
    const float* be3  = (const float*)d_in[8];
    float* out = (float*)d_out;
    float* ws  = (float*)d_ws;

    unsigned short* qkvb  = (unsigned short*)(ws + OFF_QKV);
    float* a1    = ws + OFF_A1;
    float* b1    = ws + OFF_B1;
    float* p2    = ws + OFF_P2;
    unsigned short* attnb  = (unsigned short*)(ws + OFF_ATTN);
    unsigned short* attneb = (unsigned short*)(ws + OFF_ATTNE);
    float* a3    = ws + OFF_A3;
    float* b3    = ws + OFF_B3;
    unsigned short* imgQK = (unsigned short*)(ws + OFF_IMGQ);
    unsigned short* imgV  = (unsigned short*)(ws + OFF_IMGV);
    u64* zqk = (u64*)(ws + OFF_ZQK);
    u64* zqe = (u64*)(ws + OFF_ZQE);
    u64* zke = (u64*)(ws + OFF_ZKE);
    unsigned short* xTh = (unsigned short*)(ws + OFF_XTH);
    unsigned short* wh  = (unsigned short*)(ws + OFF_WH);
    unsigned short* wl  = (unsigned short*)(ws + OFF_WL);

    const int SHM_A = 26720;
    const int SHM_B = 33296;
    k_prep<<<385, 256, 0, stream>>>(x, w, remb, xTh, wh, wl, imgQK, imgV);
    k_qkv_mfma<<<dim3(4, 128), 512, 0, stream>>>(wh, wl, xTh, qkvb);
    k_bn1<<<512, 256, 0, stream>>>(qkvb, g1, be1, a1, b1);
    k_pass2<0><<<4096, 256, SHM_A, stream>>>(qkvb, a1, b1, imgQK, imgV, p2, nullptr, zqk, zqe, zke, nullptr, nullptr);
    k_pass2<1><<<4096, 256, SHM_B, stream>>>(qkvb, a1, b1, imgQK, imgV, p2, g2, zqk, zqe, zke, attnb, attneb);
    k_bn3<<<512, 256, 0, stream>>>(attnb, attneb, g3, be3, a3, b3);
    k_out<<<2048, 256, 0, stream>>>(attnb, attneb, a3, b3, out);
}

// Round 16
// 101.504 us; speedup vs baseline: 1.2284x; 1.0524x over previous
//
#include <hip/hip_runtime.h>
#include <hip/hip_bf16.h>

typedef short s16x8 __attribute__((ext_vector_type(8)));
typedef float f32x4 __attribute__((ext_vector_type(4)));
typedef unsigned long long u64;

static __device__ __forceinline__ unsigned short f2bf(float f){
    unsigned int u = __float_as_uint(f);
    u += 0x7fffu + ((u >> 16) & 1u);
    return (unsigned short)(u >> 16);
}
static __device__ __forceinline__ float bf2f(unsigned short h){
    return __uint_as_float(((unsigned int)h) << 16);
}

// ---------------- workspace layout (float offsets) ----------------
static const size_t OFF_QKV   = 0;         // bf16[256][512][64]
static const size_t OFF_A1    = 8388608;
static const size_t OFF_B1    = 8389120;
static const size_t OFF_P2    = 8389632;
static const size_t OFF_A2    = 8414208;
static const size_t OFF_ATTN  = 8414272;   // bf16[256][16][16][64]
static const size_t OFF_ATTNE = 12608576;  // bf16[256][16][16][64]
static const size_t OFF_A3    = 16802880;
static const size_t OFF_B3    = 16803392;
static const size_t OFF_IMGQ  = 16803904;  // u16[128][24]
static const size_t OFF_IMGV  = 16805440;  // u16[16][136]
static const size_t OFF_ZQK   = 16806528;  // u64[4096][256][4]
static const size_t OFF_ZQE   = 25195136;
static const size_t OFF_ZKE   = 33583744;
// transients (dead before pass2<1> writes attn/attne):
static const size_t OFF_XTH = OFF_ATTN;               // bf16[16384][256]
static const size_t OFF_WH  = OFF_ATTN + 4194304;     // bf16[512][256]
static const size_t OFF_WL  = OFF_ATTN + 4259840;     // bf16[512][256]

// ---------------- Kernel 0: prep (x transpose | w split | rel_emb images) ----------------
__global__ __launch_bounds__(256) void k_prep(const float* __restrict__ x,
                                              const float* __restrict__ w,
                                              const float* __restrict__ remb,
                                              unsigned short* __restrict__ xTh,
                                              unsigned short* __restrict__ wh,
                                              unsigned short* __restrict__ wl,
                                              unsigned short* __restrict__ imgQK,
                                              unsigned short* __restrict__ imgV)
{
    const int bid = blockIdx.x;
    const int tid = threadIdx.x;
    if (bid < 256) {           // ---- split+transpose x
        __shared__ unsigned short xs[64*264];
        const int n = bid;
        const int b = n >> 6, h = n & 63;
        const float* xbase = x + (size_t)b*256*4096 + (size_t)h*64;
        const int iw = tid >> 2, cch = (tid & 3) * 64;
        const size_t row = (size_t)n*64 + iw;
        {
            const int c = tid;
            #pragma unroll 4
            for (int ic = 0; ic < 16; ++ic) {
                const float4 v = *(const float4*)&xbase[(size_t)c*4096 + ic*4];
                const float vv[4] = {v.x, v.y, v.z, v.w};
                #pragma unroll
                for (int u = 0; u < 4; ++u) xs[(ic*4+u)*264 + c] = f2bf(vv[u]);
            }
        }
        __syncthreads();
        #pragma unroll
        for (int u8 = 0; u8 < 8; ++u8)
            *(s16x8*)&xTh[row*256 + cch + u8*8] = *(const s16x8*)&xs[iw*264 + cch + u8*8];
        return;
    }
    if (bid < 384) {           // ---- split w
        const int t4 = (bid - 256)*256 + tid;
        const float4 v = *(const float4*)&w[(size_t)t4*4];
        const float vv[4] = {v.x, v.y, v.z, v.w};
        ushort4 hi4, lo4;
        unsigned short* hp = (unsigned short*)&hi4;
        unsigned short* lp = (unsigned short*)&lo4;
        #pragma unroll
        for (int u = 0; u < 4; ++u) {
            hp[u] = f2bf(vv[u]);
            lp[u] = f2bf(vv[u] - bf2f(hp[u]));
        }
        *(ushort4*)&wh[(size_t)t4*4] = hi4;
        *(ushort4*)&wl[(size_t)t4*4] = lo4;
        return;
    }
    // bid == 384: rel_emb images
    if (tid < 128) {
        const int d = tid;
        u64 q0 = 0, q1 = 0, k0 = 0, k1 = 0;
        if (d < 127) {
            #pragma unroll
            for (int c = 0; c < 4; ++c) q0 |= (u64)f2bf(remb[c*127 + d])      << (16*c);
            #pragma unroll
            for (int c = 0; c < 4; ++c) q1 |= (u64)f2bf(remb[(4+c)*127 + d])  << (16*c);
            #pragma unroll
            for (int c = 0; c < 4; ++c) k0 |= (u64)f2bf(remb[(8+c)*127 + d])  << (16*c);
            #pragma unroll
            for (int c = 0; c < 4; ++c) k1 |= (u64)f2bf(remb[(12+c)*127 + d]) << (16*c);
        }
        u64* row = (u64*)(imgQK + (size_t)d*24);
        row[0] = q0; row[1] = q1; row[2] = k0; row[3] = k1; row[4] = 0; row[5] = 0;
    } else {
        for (int e = tid - 128; e < 2176; e += 128) {
            const int cv = e / 136, dd = e - cv*136;
            imgV[e] = (dd < 127) ? f2bf(remb[(16+cv)*127 + dd]) : (unsigned short)0;
        }
    }
}

// ---------------- Kernel 1: qkv(bf16) = (wh+wl).xh via MFMA ----------------
__global__ __launch_bounds__(512) void k_qkv_mfma(const unsigned short* __restrict__ wh,
                                                  const unsigned short* __restrict__ wl,
                                                  const unsigned short* __restrict__ xTh,
                                                  unsigned short* __restrict__ qkvb)
{
    __shared__ char smraw[34816];
    unsigned short* const Ah = (unsigned short*)smraw;           // [128][40]
    unsigned short* const Al = Ah + 5120;
    unsigned short* const Bh = Al + 5120;
    unsigned short* const Cl = (unsigned short*)smraw;           // [128][136] overlay
    const int o0   = blockIdx.x * 128;
    const int col0 = blockIdx.y * 128;
    const int tid = threadIdx.x;
    const int w = tid >> 6, l = tid & 63, lb = l & 15, h = l >> 4;
    const int oq = (w >> 2) * 64, cq = (w & 3) * 32;

    f32x4 acc[4][2];
    #pragma unroll
    for (int m = 0; m < 4; ++m)
        #pragma unroll
        for (int nn = 0; nn < 2; ++nn) { acc[m][nn][0]=0.f; acc[m][nn][1]=0.f; acc[m][nn][2]=0.f; acc[m][nn][3]=0.f; }

    const int srow = tid >> 2, sc8 = (tid & 3) * 8;
    int4 rA, rL, rB;
    rA = *(const int4*)(wh  + (size_t)(o0  +srow)*256 + sc8);
    rL = *(const int4*)(wl  + (size_t)(o0  +srow)*256 + sc8);
    rB = *(const int4*)(xTh + (size_t)(col0+srow)*256 + sc8);
    *(int4*)&Ah[srow*40 + sc8] = rA;
    *(int4*)&Al[srow*40 + sc8] = rL;
    *(int4*)&Bh[srow*40 + sc8] = rB;

    for (int step = 0; step < 8; ++step) {
        __syncthreads();
        if (step < 7) {
            const int kk = (step+1)*32;
            rA = *(const int4*)(wh  + (size_t)(o0  +srow)*256 + kk + sc8);
            rL = *(const int4*)(wl  + (size_t)(o0  +srow)*256 + kk + sc8);
            rB = *(const int4*)(xTh + (size_t)(col0+srow)*256 + kk + sc8);
        }
        s16x8 ah[4], al[4], bf[2];
        #pragma unroll
        for (int m = 0; m < 4; ++m)  ah[m] = *(const s16x8*)&Ah[(oq + m*16 + lb)*40 + h*8];
        #pragma unroll
        for (int m = 0; m < 4; ++m)  al[m] = *(const s16x8*)&Al[(oq + m*16 + lb)*40 + h*8];
        #pragma unroll
        for (int nn = 0; nn < 2; ++nn) bf[nn] = *(const s16x8*)&Bh[(cq + nn*16 + lb)*40 + h*8];
        #pragma unroll
        for (int m = 0; m < 4; ++m)
            #pragma unroll
            for (int nn = 0; nn < 2; ++nn) {
                acc[m][nn] = __builtin_amdgcn_mfma_f32_16x16x32_bf16(ah[m], bf[nn], acc[m][nn], 0,0,0);
                acc[m][nn] = __builtin_amdgcn_mfma_f32_16x16x32_bf16(al[m], bf[nn], acc[m][nn], 0,0,0);
            }
        __syncthreads();
        if (step < 7) {
            *(int4*)&Ah[srow*40 + sc8] = rA;
            *(int4*)&Al[srow*40 + sc8] = rL;
            *(int4*)&Bh[srow*40 + sc8] = rB;
        }
    }

    #pragma unroll
    for (int m = 0; m < 4; ++m)
        #pragma unroll
        for (int nn = 0; nn < 2; ++nn)
            #pragma unroll
            for (int r = 0; r < 4; ++r)
                Cl[(oq + m*16 + h*4 + r)*136 + cq + nn*16 + lb] = f2bf(acc[m][nn][r]);
    __syncthreads();
    const int erow = tid >> 2, eseg = (tid & 3) * 16;
    #pragma unroll
    for (int h2 = 0; h2 < 2; ++h2) {
        unsigned short* dst = qkvb + ((size_t)((col0 >> 6) + h2)*512 + (o0 + erow))*64 + eseg;
        *(s16x8*)&dst[0] = *(const s16x8*)&Cl[erow*136 + h2*64 + eseg];
        *(s16x8*)&dst[8] = *(const s16x8*)&Cl[erow*136 + h2*64 + eseg + 8];
    }
}

// ---------------- Kernel 2: bn1 stats (bf16 qkv) -> folded affine a1,b1 ----------------
__global__ __launch_bounds__(256) void k_bn1(const unsigned short* __restrict__ qkvb,
                                             const float* __restrict__ gamma,
                                             const float* __restrict__ beta,
                                             float* __restrict__ a1, float* __restrict__ b1)
{
    const int o = blockIdx.x;
    const int tid = threadIdx.x;
    float s = 0.f, s2 = 0.f;
    for (int t = tid; t < 2048; t += 256) {
        const int n = t >> 3, i8 = (t & 7) * 8;
        const s16x8 v8 = *(const s16x8*)&qkvb[((size_t)n*512 + o)*64 + i8];
        #pragma unroll
        for (int j = 0; j < 8; ++j) {
            const float f = bf2f((unsigned short)v8[j]);
            s += f; s2 += f*f;
        }
    }
    __shared__ float rs[4], rs2[4];
    #pragma unroll
    for (int off = 32; off; off >>= 1) { s += __shfl_down(s, off); s2 += __shfl_down(s2, off); }
    if ((tid & 63) == 0) { rs[tid>>6] = s; rs2[tid>>6] = s2; }
    __syncthreads();
    if (tid == 0) {
        const float S  = rs[0]+rs[1]+rs[2]+rs[3];
        const float S2 = rs2[0]+rs2[1]+rs2[2]+rs2[3];
        const float mean = S * (1.f/16384.f);
        const float var  = S2 * (1.f/16384.f) - mean*mean;
        const float A = gamma[o] * rsqrtf(var + 1e-5f);
        a1[o] = A;
        b1[o] = beta[o] - mean*A;
    }
}

// ---------------- Kernels 3/5: per-(n,g) core (round-12 verified) ----------------
template<int PASSB>
__global__ __launch_bounds__(256) void k_pass2(const unsigned short* __restrict__ qkvb,
    const float* __restrict__ a1, const float* __restrict__ b1,
    const unsigned short* __restrict__ imgQK, const unsigned short* __restrict__ imgV,
    float* __restrict__ p2, const float* __restrict__ a2,
    u64* __restrict__ zqk, u64* __restrict__ zqe, u64* __restrict__ zke,
    unsigned short* __restrict__ attnb, unsigned short* __restrict__ attneb)
{
    extern __shared__ char sm[];
    const int bx = blockIdx.x, n = bx >> 4, g = bx & 15;
    const int tid = threadIdx.x;
    const int w = tid >> 6, l = tid & 63, lb = l & 15, h = l >> 4;
    const int i0 = w*16;
    const size_t bbase = ((size_t)bx*256 + tid)*4;
    const s16x8 z8 = {0,0,0,0,0,0,0,0};

    if (!PASSB) {
        unsigned short* const qkT    = (unsigned short*)sm;            // [64][16]
        unsigned short* const rembQK = (unsigned short*)(sm + 2048);   // [128][24]
        unsigned short (* const qeT)[72] = (unsigned short(*)[72])(sm + 8192);
        unsigned short (* const keT)[72] = (unsigned short(*)[72])(sm + 17408);
        float* const red = (float*)(sm + 26624);

        {
            const int4* gsrc = (const int4*)imgQK;
            int4* ldst = (int4*)rembQK;
            for (int t = tid; t < 384; t += 256) ldst[t] = gsrc[t];
        }
        {
            const int a = tid & 63, c0 = (tid >> 6) * 4;
            u64 pk = 0;
            #pragma unroll
            for (int u = 0; u < 4; ++u) {
                const int o = g*32 + c0 + u;
                const float val = a1[o] * bf2f(qkvb[((size_t)n*512 + o)*64 + a]) + b1[o];
                pk |= (u64)f2bf(val) << (16*u);
            }
            *(u64*)&qkT[a*16 + c0] = pk;
        }
        __syncthreads();

        float sqe=0.f, s2qe=0.f, ske=0.f, s2ke=0.f;
        {
            const int a0 = w*16;
            const s16x8 afr = (h < 2) ? *(const s16x8*)&qkT[(a0 + lb)*16 + h*8] : z8;
            #pragma unroll
            for (int dt = 0; dt < 8; ++dt) {
                const int dd = dt*16 + lb;
                const s16x8 bq = (h == 0) ? *(const s16x8*)&rembQK[dd*24 + 0] : z8;
                const s16x8 bk = (h == 1) ? *(const s16x8*)&rembQK[dd*24 + 8] : z8;
                f32x4 zz = {0.f,0.f,0.f,0.f};
                f32x4 cqf = __builtin_amdgcn_mfma_f32_16x16x32_bf16(afr, bq, zz, 0,0,0);
                f32x4 ckf = __builtin_amdgcn_mfma_f32_16x16x32_bf16(afr, bk, zz, 0,0,0);
                #pragma unroll
                for (int r = 0; r < 4; ++r) {
                    const int a = a0 + h*4 + r;
                    const int i = a + 63 - dd;
                    if (i >= 0 && i < 64) {
                        const float vq = cqf[r], vk = ckf[r];
                        qeT[i][a] = f2bf(vq);
                        keT[i][a] = f2bf(vk);
                        sqe += vq; s2qe += vq*vq; ske += vk; s2ke += vk*vk;
                    }
                }
            }
        }
        __syncthreads();

        f32x4 acc[4];
        #pragma unroll
        for (int jt = 0; jt < 4; ++jt) { acc[jt][0]=0.f; acc[jt][1]=0.f; acc[jt][2]=0.f; acc[jt][3]=0.f; }
        #pragma unroll
        for (int kc = 0; kc < 2; ++kc) {
            const s16x8 aq = *(const s16x8*)&qeT[i0 + lb][kc*32 + h*8];
            #pragma unroll
            for (int jt = 0; jt < 4; ++jt) {
                const s16x8 bk2 = *(const s16x8*)&keT[jt*16 + lb][kc*32 + h*8];
                acc[jt] = __builtin_amdgcn_mfma_f32_16x16x32_bf16(aq, bk2, acc[jt], 0,0,0);
            }
        }

        float sqk=0.f, s2qk=0.f;
        #pragma unroll
        for (int jt = 0; jt < 4; ++jt) {
            const u64 q4 = *(const u64*)&qeT[jt*16 + lb][i0 + 4*h];
            const u64 k4 = *(const u64*)&keT[jt*16 + lb][i0 + 4*h];
            zqe[bbase + jt] = q4;
            zke[bbase + jt] = k4;
            u64 pk = 0;
            #pragma unroll
            for (int r = 0; r < 4; ++r) {
                const float q_ = acc[jt][r];
                sqk += q_; s2qk += q_*q_;
                pk |= (u64)f2bf(q_) << (16*r);
            }
            zqk[bbase + jt] = pk;
        }

        float vals[6] = {sqk, s2qk, sqe, s2qe, ske, s2ke};
        #pragma unroll
        for (int q = 0; q < 6; ++q) {
            float v = vals[q];
            #pragma unroll
            for (int off = 32; off; off >>= 1) v += __shfl_xor(v, off);
            if (l == 0) red[w*6 + q] = v;
        }
        __syncthreads();
        if (tid < 6) p2[(size_t)bx*6 + tid] = red[tid] + red[6+tid] + red[12+tid] + red[18+tid];
        return;
    }

    // ================= PASS B =================
    unsigned short (* const PSt)[136]   = (unsigned short(*)[136])(sm);
    unsigned short (* const pT)[72]     = (unsigned short(*)[72])(sm + 17408);
    unsigned short (* const rembV)[136] = (unsigned short(*)[136])(sm + 26624);
    unsigned short (* const vbL)[72]    = (unsigned short(*)[72])(sm + 30976);

    {
        int4 z4i; z4i.x=z4i.y=z4i.z=z4i.w=0;
        int4* dst = (int4*)sm;
        for (int t = tid; t < 1088; t += 256) dst[t] = z4i;
    }
    {
        const int4* gsrc = (const int4*)imgV;
        int4* ldst = (int4*)rembV;
        for (int t = tid; t < 272; t += 256) ldst[t] = gsrc[t];
    }
    {
        const int cv = tid >> 4, ap = (tid & 15) * 4;
        const int o = g*32 + 16 + cv;
        const float A = a1[o], Bc = b1[o];
        const ushort4 vv = *(const ushort4*)&qkvb[((size_t)n*512 + o)*64 + ap];
        u64 pk = 0;
        pk |= (u64)f2bf(A*bf2f(vv.x) + Bc);
        pk |= (u64)f2bf(A*bf2f(vv.y) + Bc) << 16;
        pk |= (u64)f2bf(A*bf2f(vv.z) + Bc) << 32;
        pk |= (u64)f2bf(A*bf2f(vv.w) + Bc) << 48;
        *(u64*)&vbL[cv][ap] = pk;
    }

    const float c_qk = a2[g], c_qe = a2[16+g], c_ke = a2[32+g];
    float p[4][4];
    #pragma unroll
    for (int jt = 0; jt < 4; ++jt) {
        const u64 zq = zqk[bbase + jt];
        const u64 q4 = zqe[bbase + jt];
        const u64 k4 = zke[bbase + jt];
        #pragma unroll
        for (int r = 0; r < 4; ++r) {
            p[jt][r] = c_qk*bf2f((unsigned short)(zq >> (16*r)))
                     + c_qe*bf2f((unsigned short)(q4 >> (16*r)))
                     + c_ke*bf2f((unsigned short)(k4 >> (16*r)));
        }
    }
    #pragma unroll
    for (int r = 0; r < 4; ++r) {
        float m = fmaxf(fmaxf(p[0][r], p[1][r]), fmaxf(p[2][r], p[3][r]));
        #pragma unroll
        for (int mk = 8; mk; mk >>= 1) m = fmaxf(m, __shfl_xor(m, mk));
        float s = 0.f;
        #pragma unroll
        for (int jt = 0; jt < 4; ++jt) { p[jt][r] = __expf(p[jt][r] - m); s += p[jt][r]; }
        #pragma unroll
        for (int mk = 8; mk; mk >>= 1) s += __shfl_xor(s, mk);
        const float inv = 1.f / s;
        #pragma unroll
        for (int jt = 0; jt < 4; ++jt) p[jt][r] *= inv;
    }
    __syncthreads();

    #pragma unroll
    for (int jt = 0; jt < 4; ++jt)
        #pragma unroll
        for (int r = 0; r < 4; ++r) {
            const int i = i0 + 4*h + r, j = jt*16 + lb;
            const unsigned short pb = f2bf(p[jt][r]);
            pT[i][j] = pb;
            PSt[i][i + 63 - j] = pb;
        }
    __syncthreads();

    f32x4 accA = {0.f,0.f,0.f,0.f}, accE = {0.f,0.f,0.f,0.f};
    #pragma unroll
    for (int kc = 0; kc < 2; ++kc) {
        const s16x8 av = *(const s16x8*)&vbL[lb][kc*32 + h*8];
        const s16x8 bp = *(const s16x8*)&pT[i0 + lb][kc*32 + h*8];
        accA = __builtin_amdgcn_mfma_f32_16x16x32_bf16(av, bp, accA, 0,0,0);
    }
    #pragma unroll
    for (int kc = 0; kc < 4; ++kc) {
        const s16x8 ae = *(const s16x8*)&rembV[lb][kc*32 + h*8];
        const s16x8 bs = *(const s16x8*)&PSt[i0 + lb][kc*32 + h*8];
        accE = __builtin_amdgcn_mfma_f32_16x16x32_bf16(ae, bs, accE, 0,0,0);
    }
    unsigned short* aw = attnb  + ((size_t)n*16 + g)*1024;
    unsigned short* ew = attneb + ((size_t)n*16 + g)*1024;
    #pragma unroll
    for (int r = 0; r < 4; ++r) {
        aw[(4*h + r)*64 + i0 + lb] = f2bf(accA[r]);
        ew[(4*h + r)*64 + i0 + lb] = f2bf(accE[r]);
    }
}

// ---------------- Kernel 4: bn2 finalize (12 blocks x 4 waves = 48 ch) ----------------
__global__ __launch_bounds__(256) void k_bn2(const float* __restrict__ p2,
                                             const float* __restrict__ gamma2,
                                             float* __restrict__ a2)
{
    const int ch = blockIdx.x*4 + (threadIdx.x >> 6);
    const int l = threadIdx.x & 63;
    const int kind = ch >> 4, g = ch & 15;
    float s = 0.f, s2 = 0.f;
    #pragma unroll
    for (int q = 0; q < 4; ++q) {
        const int nn = q*64 + l;
        const float* p = p2 + ((size_t)nn*16 + g)*6 + 2*kind;
        s += p[0]; s2 += p[1];
    }
    #pragma unroll
    for (int off = 32; off; off >>= 1) { s += __shfl_down(s, off); s2 += __shfl_down(s2, off); }
    if (l == 0) {
        const float mean = s * (1.f/1048576.f);
        const float var  = s2 * (1.f/1048576.f) - mean*mean;
        a2[ch] = gamma2[ch] * rsqrtf(var + 1e-5f);
    }
}

// ---------------- Kernel 6: bn3 stats (bf16 attn) -> a3,b3 ----------------
__global__ __launch_bounds__(256) void k_bn3(const unsigned short* __restrict__ attnb,
                                             const unsigned short* __restrict__ attneb,
                                             const float* __restrict__ gamma,
                                             const float* __restrict__ beta,
                                             float* __restrict__ a3, float* __restrict__ b3)
{
    const int o = blockIdx.x;
    const int g = o >> 5, rem = o & 31, c = rem >> 1, sflag = rem & 1;
    const unsigned short* src = (sflag ? attneb : attnb) + (size_t)g*1024 + (size_t)c*64;
    const int tid = threadIdx.x;
    float s = 0.f, s2 = 0.f;
    for (int t = tid; t < 2048; t += 256) {
        const int n = t >> 3, i8 = (t & 7) * 8;
        const s16x8 v8 = *(const s16x8*)&src[(size_t)n*16384 + i8];
        #pragma unroll
        for (int j = 0; j < 8; ++j) {
            const float f = bf2f((unsigned short)v8[j]);
            s += f; s2 += f*f;
        }
    }
    __shared__ float rs[4], rs2[4];
    #pragma unroll
    for (int off = 32; off; off >>= 1) { s += __shfl_down(s, off); s2 += __shfl_down(s2, off); }
    if ((tid & 63) == 0) { rs[tid>>6] = s; rs2[tid>>6] = s2; }
    __syncthreads();
    if (tid == 0) {
        const float S  = rs[0]+rs[1]+rs[2]+rs[3];
        const float S2 = rs2[0]+rs2[1]+rs2[2]+rs2[3];
        const float mean = S * (1.f/16384.f);
        const float var  = S2 * (1.f/16384.f) - mean*mean;
        const float A = gamma[o] * rsqrtf(var + 1e-5f);
        a3[o] = A;
        b3[o] = beta[o] - mean*A;
    }
}

// ---------------- Kernel 7: apply bn3, sum channel pairs, transpose (8-wide) ----------------
__global__ __launch_bounds__(256) void k_out(const unsigned short* __restrict__ attnb,
                                             const unsigned short* __restrict__ attneb,
                                             const float* __restrict__ a3,
                                             const float* __restrict__ b3,
                                             float* __restrict__ out)
{
    const int idx8 = blockIdx.x*256 + threadIdx.x;   // 524,288 octets
    const int i8 = (idx8 & 7) * 8;
    const int h  = (idx8 >> 3) & 63;
    const int oc = (idx8 >> 9) & 255;
    const int b  = idx8 >> 17;
    const int g = oc >> 4, c = oc & 15;
    const int n = b*64 + h;
    const size_t src = ((size_t)n*16 + g)*1024 + (size_t)c*64 + i8;
    const int o0 = g*32 + 2*c;
    const float A0 = a3[o0], A1 = a3[o0+1], Bc = b3[o0] + b3[o0+1];
    const s16x8 va = *(const s16x8*)&attnb[src];
    const s16x8 ve = *(const s16x8*)&attneb[src];
    float res[8];
    #pragma unroll
    for (int j = 0; j < 8; ++j)
        res[j] = A0*bf2f((unsigned short)va[j]) + A1*bf2f((unsigned short)ve[j]) + Bc;
    float* dst = &out[((size_t)b*256 + oc)*4096 + h*64 + i8];
    *(float4*)&dst[0] = make_float4(res[0], res[1], res[2], res[3]);
    *(float4*)&dst[4] = make_float4(res[4], res[5], res[6], res[7]);
}

extern "C" void kernel_launch(void* const* d_in, const int* in_sizes, int n_in,
                              void* d_out, int out_size, void* d_ws, size_t ws_size,
                              hipStream_t stream) {
    const float* x    = (const float*)d_in[0];
    const float* w    = (const float*)d_in[1];
    const float* g1   = (const float*)d_in[2];
    const float* be1  = (const float*)d_in[3];
    const float* remb = (const float*)d_in[4];
    const float* g2   = (const float*)d_in[5];
    const float* g3   = (const float*)d_in[7];
    const float* be3  = (const float*)d_in[8];
    float* out = (float*)d_out;
    float* ws  = (float*)d_ws;

    unsigned short* qkvb  = (unsigned short*)(ws + OFF_QKV);
    float* a1    = ws + OFF_A1;
    float* b1    = ws + OFF_B1;
    float* p2    = ws + OFF_P2;
    float* a2    = ws + OFF_A2;
    unsigned short* attnb  = (unsigned short*)(ws + OFF_ATTN);
    unsigned short* attneb = (unsigned short*)(ws + OFF_ATTNE);
    float* a3    = ws + OFF_A3;
    float* b3    = ws + OFF_B3;
    unsigned short* imgQK = (unsigned short*)(ws + OFF_IMGQ);
    unsigned short* imgV  = (unsigned short*)(ws + OFF_IMGV);
    u64* zqk = (u64*)(ws + OFF_ZQK);
    u64* zqe = (u64*)(ws + OFF_ZQE);
    u64* zke = (u64*)(ws + OFF_ZKE);
    unsigned short* xTh = (unsigned short*)(ws + OFF_XTH);
    unsigned short* wh  = (unsigned short*)(ws + OFF_WH);
    unsigned short* wl  = (unsigned short*)(ws + OFF_WL);

    const int SHM_A = 26720;
    const int SHM_B = 33280;
    k_prep<<<385, 256, 0, stream>>>(x, w, remb, xTh, wh, wl, imgQK, imgV);
    k_qkv_mfma<<<dim3(4, 128), 512, 0, stream>>>(wh, wl, xTh, qkvb);
    k_bn1<<<512, 256, 0, stream>>>(qkvb, g1, be1, a1, b1);
    k_pass2<0><<<4096, 256, SHM_A, stream>>>(qkvb, a1, b1, imgQK, imgV, p2, nullptr, zqk, zqe, zke, nullptr, nullptr);
    k_bn2<<<12, 256, 0, stream>>>(p2, g2, a2);
    k_pass2<1><<<4096, 256, SHM_B, stream>>>(qkvb, a1, b1, imgQK, imgV, nullptr, a2, zqk, zqe, zke, attnb, attneb);
    k_bn3<<<512, 256, 0, stream>>>(attnb, attneb, g3, be3, a3, b3);
    k_out<<<2048, 256, 0, stream>>>(attnb, attneb, a3, b3, out);
}